// Round 7
// baseline (93.572 us; speedup 1.0000x reference)
//
#include <hip/hip_runtime.h>
#include <hip/hip_fp16.h>

typedef __attribute__((ext_vector_type(8))) short short8;
typedef __attribute__((ext_vector_type(8))) __bf16 bf16x8;
typedef __attribute__((ext_vector_type(4))) float f32x4;
typedef __attribute__((ext_vector_type(16))) float f32x16;

#define DEV __device__ __forceinline__

DEV unsigned short f2bf(float f) {
    unsigned int u = __float_as_uint(f);
    return (unsigned short)((u + 0x7FFFu + ((u >> 16) & 1u)) >> 16);
}
DEV float bf2f(unsigned short s) { return __uint_as_float(((unsigned int)s) << 16); }
DEV bf16x8 asbf(short8 v) { return __builtin_bit_cast(bf16x8, v); }

// ---------------- prep kernel (feat cast + weight pack fused) ----------------
__global__ __launch_bounds__(256) void k_prep(const float* __restrict__ feat,
                                              const float* __restrict__ qw, const float* __restrict__ qb,
                                              const float* __restrict__ kvw, const float* __restrict__ kvb,
                                              const float* __restrict__ pew, const float* __restrict__ peb,
                                              const float* __restrict__ pret, const float* __restrict__ projw,
                                              unsigned short* __restrict__ featb,
                                              unsigned short* __restrict__ wqkv, float* __restrict__ bqkv,
                                              unsigned short* __restrict__ projwb, unsigned short* __restrict__ peAll) {
    const float scale = 0.17677669529663687f; // 1/sqrt(32)
    int i0 = blockIdx.x * 256 + threadIdx.x;
    if (i0 < 262144) {                        // feat f32 -> bf16, 8/thread
        const float4* f4 = (const float4*)feat + (size_t)i0 * 2;
        float4 a = f4[0], c = f4[1];
        short8 o;
        o[0] = (short)f2bf(a.x); o[1] = (short)f2bf(a.y);
        o[2] = (short)f2bf(a.z); o[3] = (short)f2bf(a.w);
        o[4] = (short)f2bf(c.x); o[5] = (short)f2bf(c.y);
        o[6] = (short)f2bf(c.z); o[7] = (short)f2bf(c.w);
        ((short8*)featb)[i0] = o;
        return;
    }
    int i = i0 - 262144;
    if (i < 786432) {                         // wqkv [1536][512]
        int o = i >> 9, k = i & 511;
        float v = (o < 512) ? qw[(o << 9) + k] * scale : kvw[((o - 512) << 9) + k];
        wqkv[i] = f2bf(v);
    } else if (i < 786432 + 262144) {
        int j = i - 786432;
        projwb[j] = f2bf(projw[j]);
    } else if (i < 786432 + 262144 + 1536) {
        int o = i - (786432 + 262144);
        bqkv[o] = (o < 512) ? qb[o] * scale : kvb[o - 512];
    } else if (i < 786432 + 262144 + 1536 + 65536) { // peAll[t][16] f16
        int j = i - (786432 + 262144 + 1536);
        int t = j >> 4, h = j & 15;
        float s = peb[h];
#pragma unroll
        for (int u = 0; u < 5; u++) s += pret[t * 5 + u] * pew[h * 5 + u];
        peAll[j] = __builtin_bit_cast(unsigned short, __float2half(s));
    }
}

// ---------------- QKV GEMM: 128x128 tile, 512 threads (epilogue scatters frag order) ----------------
// Qf: [bh][qt(32)][sub(2)][lane(64)][8]   q = qt*32+q5, d = sub*16+hi*8+j, lane=hi*32+q5
// Kf: [bh][kt(16)][ks(2)][half(2)][lane][8]  n = kt*64+ks*32+q5, d = half*16+hi*8+j
// Vf: [bh][kt(16)][ks(2)][half(2)][lane][8]  d = q5, n = kt*64+ks*32+half*16+hi*8+j
__global__ __launch_bounds__(512, 2) void k_qkv(const unsigned short* __restrict__ A,
                                                const unsigned short* __restrict__ Bw,
                                                const float* __restrict__ bias,
                                                unsigned short* __restrict__ Qf,
                                                unsigned short* __restrict__ Kf,
                                                unsigned short* __restrict__ Vf) {
    __shared__ __align__(16) unsigned short As[128][72];
    __shared__ __align__(16) unsigned short Bs[128][72];
    int tid = threadIdx.x, lane = tid & 63, wid = tid >> 6;
    int m0 = blockIdx.y * 128, n0 = blockIdx.x * 128;
    int wm = wid & 3, wn = wid >> 2;
    f32x4 acc[2][4] = {};

    for (int k0 = 0; k0 < 512; k0 += 64) {
        {
            int row = tid >> 2, cs = (tid & 3) * 16;
            const short8* srcA = (const short8*)(A + (size_t)(m0 + row) * 512 + k0 + cs);
            short8* dstA = (short8*)(&As[row][cs]);
            dstA[0] = srcA[0]; dstA[1] = srcA[1];
            const short8* srcB = (const short8*)(Bw + (size_t)(n0 + row) * 512 + k0 + cs);
            short8* dstB = (short8*)(&Bs[row][cs]);
            dstB[0] = srcB[0]; dstB[1] = srcB[1];
        }
        __syncthreads();
#pragma unroll
        for (int kk = 0; kk < 64; kk += 32) {
            short8 a[2], b[4];
#pragma unroll
            for (int m = 0; m < 2; m++)
                a[m] = *(const short8*)(&As[wm * 32 + m * 16 + (lane & 15)][kk + ((lane >> 4) << 3)]);
#pragma unroll
            for (int n = 0; n < 4; n++)
                b[n] = *(const short8*)(&Bs[wn * 64 + n * 16 + (lane & 15)][kk + ((lane >> 4) << 3)]);
#pragma unroll
            for (int m = 0; m < 2; m++) {
#pragma unroll
                for (int n = 0; n < 4; n++)
                    acc[m][n] = __builtin_amdgcn_mfma_f32_16x16x32_bf16(asbf(a[m]), asbf(b[n]), acc[m][n], 0, 0, 0);
            }
        }
        __syncthreads();
    }
#pragma unroll
    for (int m = 0; m < 2; m++) {
#pragma unroll
        for (int n = 0; n < 4; n++) {
            int col = n0 + wn * 64 + n * 16 + (lane & 15);
            float bv = bias[col];
#pragma unroll
            for (int r = 0; r < 4; r++) {
                int row = m0 + wm * 32 + m * 16 + ((lane >> 4) << 2) + r;
                float v = acc[m][n][r] + bv;
                unsigned short bb = f2bf(v);
                int batch = row >> 10, nn = row & 1023;
                if (col < 512) {            // Q
                    int h = col >> 5, d = col & 31;
                    int bh = (batch << 4) + h;
                    int qt = nn >> 5, q5 = nn & 31;
                    int sub = d >> 4, hi2 = (d >> 3) & 1, j = d & 7;
                    Qf[((((size_t)(bh * 32 + qt) * 2 + sub) * 64) + hi2 * 32 + q5) * 8 + j] = bb;
                } else {
                    int oo = col - 512, h = oo >> 6, rem = oo & 63;
                    int bh = (batch << 4) + h;
                    int kt = nn >> 6, ks = (nn >> 5) & 1;
                    if (rem < 32) {         // K
                        int d = rem, half = d >> 4, hi2 = (d >> 3) & 1, j = d & 7, q5 = nn & 31;
                        Kf[((((size_t)((bh * 16 + kt) * 2 + ks) * 2 + half) * 64) + hi2 * 32 + q5) * 8 + j] = bb;
                    } else {                // V
                        int d = rem - 32, nb = nn & 31;
                        int half = nb >> 4, hi2 = (nb >> 3) & 1, j = nb & 7;
                        Vf[((((size_t)((bh * 16 + kt) * 2 + ks) * 2 + half) * 64) + hi2 * 32 + d) * 8 + j] = bb;
                    }
                }
            }
        }
    }
}

// ---------------- fused attention: single-buffer posb (38KB), 4 blocks/CU target ----------------
// grid 512: b=bid&3, qt=(bid>>2)&31, kc=(bid>>7)&1, hg=bid>>8
// 512 threads = 8 waves; wave w -> head hg*8+w; q-tile 32; k-chunk 512 in 8 tiles of 64
__global__ __launch_bounds__(512, 4) void k_attn(const unsigned short* __restrict__ Qf,
                                                 const unsigned short* __restrict__ Kf,
                                                 const unsigned short* __restrict__ Vf,
                                                 const int* __restrict__ pe_idx,
                                                 const unsigned short* __restrict__ peAll,
                                                 const float* __restrict__ blank_k,
                                                 float* __restrict__ partial,
                                                 float* __restrict__ ml,
                                                 float* __restrict__ lbuf) {
    __shared__ __align__(16) unsigned int posb[4][32][76];   // 38 KB single buffer, stride 76 (4-way max)

    int tid = threadIdx.x, lane = tid & 63, w = tid >> 6;
    int q5 = lane & 31, hi = lane >> 5;
    int bid = blockIdx.x;
    int b = bid & 3, qt = (bid >> 2) & 31, kc = (bid >> 7) & 1, hg = bid >> 8;
    int q0 = qt * 32;
    int head = hg * 8 + w, bh = (b << 4) + head;
    int slab = w >> 1, halfsel = w & 1;

    // gather-phase map: thread -> (q row, 4 consecutive k)
    int gq = tid >> 4, gk = (tid & 15) * 4;
    const int* pebase = pe_idx + ((size_t)((b << 10) + q0 + gq)) * 1024 + kc * 512 + gk;
    const unsigned short* peg = peAll + hg * 8;   // this head-group's 16B half-row

    short8 qf[2];
    float lb_, m_run, l_run;
    f32x16 accO = {};
    const f32x16 zero16 = {};

    {
        const unsigned short* qb_ = Qf + ((size_t)(bh * 32 + qt) * 2) * 512 + lane * 8;
        qf[0] = *(const short8*)(qb_);
        qf[1] = *(const short8*)(qb_ + 512);
        float dot = 0.f;
#pragma unroll
        for (int sub = 0; sub < 2; sub++) {
            const float* bk = blank_k + head * 32 + sub * 16 + hi * 8;
#pragma unroll
            for (int t = 0; t < 8; t++) dot += bf2f((unsigned short)qf[sub][t]) * bk[t];
        }
        dot += __shfl_xor(dot, 32, 64);
        lb_ = dot;
        m_run = (kc == 0) ? dot : -1e30f;
        l_run = (kc == 0) ? 1.0f : 0.0f;
    }

    // prologue: gather tile 0, write posb
    unsigned gg[4][4];
    {
        int4 idx = *(const int4*)(pebase);
        int id[4] = {idx.x, idx.y, idx.z, idx.w};
#pragma unroll
        for (int j = 0; j < 4; j++) {
            uint4 a = *(const uint4*)(peg + ((size_t)id[j] << 4));
            gg[0][j] = a.x; gg[1][j] = a.y; gg[2][j] = a.z; gg[3][j] = a.w;
        }
#pragma unroll
        for (int p = 0; p < 4; p++) {
            uint4 o = {gg[p][0], gg[p][1], gg[p][2], gg[p][3]};
            *(uint4*)&posb[p][gq][gk] = o;
        }
    }
    __syncthreads();

    for (int kt = 0; kt < 8; kt++) {
        // prefetch kt+1 gathers into regs (written to posb after end-of-tile barrier)
        if (kt < 7) {
            int4 idx = *(const int4*)(pebase + (kt + 1) * 64);
            int id[4] = {idx.x, idx.y, idx.z, idx.w};
#pragma unroll
            for (int j = 0; j < 4; j++) {
                uint4 a = *(const uint4*)(peg + ((size_t)id[j] << 4));
                gg[0][j] = a.x; gg[1][j] = a.y; gg[2][j] = a.z; gg[3][j] = a.w;
            }
        }

        int ktg = kc * 8 + kt;
        // S^T = K x Q^T (32k x 32q), rows k=(r&3)+8*(r>>2)+4*hi, col q=q5
        f32x16 st[2];
#pragma unroll
        for (int ks = 0; ks < 2; ks++) {
            const unsigned short* kp = Kf + ((size_t)((bh * 16 + ktg) * 2 + ks) * 2) * 512 + lane * 8;
            short8 kf0 = *(const short8*)(kp);
            short8 kf1 = *(const short8*)(kp + 512);
            st[ks] = __builtin_amdgcn_mfma_f32_32x32x16_bf16(asbf(kf0), asbf(qf[0]), zero16, 0, 0, 0);
            st[ks] = __builtin_amdgcn_mfma_f32_32x32x16_bf16(asbf(kf1), asbf(qf[1]), st[ks], 0, 0, 0);
        }
        // pos add (b128 slab reads)
#pragma unroll
        for (int ks = 0; ks < 2; ks++)
#pragma unroll
            for (int rr = 0; rr < 4; rr++) {
                uint4 v = *(const uint4*)&posb[slab][q5][ks * 32 + rr * 8 + hi * 4];
                unsigned pv[4] = {v.x, v.y, v.z, v.w};
#pragma unroll
                for (int c = 0; c < 4; c++) {
                    __half2 h2 = __builtin_bit_cast(__half2, pv[c]);
                    st[ks][rr * 4 + c] += halfsel ? __high2float(h2) : __low2float(h2);
                }
            }
        // tile max: tree reduction (depth 5) instead of 32-deep chain
        float tm[16];
#pragma unroll
        for (int i = 0; i < 16; i++) tm[i] = fmaxf(st[0][i], st[1][i]);
#pragma unroll
        for (int i = 0; i < 8; i++) tm[i] = fmaxf(tm[i], tm[i + 8]);
#pragma unroll
        for (int i = 0; i < 4; i++) tm[i] = fmaxf(tm[i], tm[i + 4]);
        float mx = fmaxf(fmaxf(tm[0], tm[1]), fmaxf(tm[2], tm[3]));
        mx = fmaxf(mx, __shfl_xor(mx, 32, 64));
        // defer-max (T13)
        if (!__all(mx <= m_run + 8.0f)) {
            float mn = fmaxf(m_run, mx);
            float fac = __expf(m_run - mn);
            m_run = mn;
            l_run *= fac;
#pragma unroll
            for (int r = 0; r < 16; r++) {
                int qrow = (r & 3) + 8 * (r >> 2) + 4 * hi;
                float facr = __shfl(fac, qrow, 64);
                accO[r] *= facr;
            }
        }
#pragma unroll
        for (int ks = 0; ks < 2; ks++)
#pragma unroll
            for (int r = 0; r < 16; r++)
                st[ks][r] = __expf(st[ks][r] - m_run);
        // sum: tree reduction
        float ts[16];
#pragma unroll
        for (int i = 0; i < 16; i++) ts[i] = st[0][i] + st[1][i];
#pragma unroll
        for (int i = 0; i < 8; i++) ts[i] += ts[i + 8];
#pragma unroll
        for (int i = 0; i < 4; i++) ts[i] += ts[i + 4];
        float sum = (ts[0] + ts[1]) + (ts[2] + ts[3]);
        sum += __shfl_xor(sum, 32, 64);
        l_run += sum;
        // P -> A-frag via v_cvt_pk_bf16_f32 + permlane32_swap (T12), then PV
#pragma unroll
        for (int ks = 0; ks < 2; ks++) {
            unsigned pk_[8];
#pragma unroll
            for (int i = 0; i < 8; i++) {
                float plo = st[ks][2 * i], phi = st[ks][2 * i + 1];
                asm("v_cvt_pk_bf16_f32 %0, %1, %2" : "=v"(pk_[i]) : "v"(plo), "v"(phi));
            }
            asm("v_permlane32_swap_b32 %0, %1" : "+v"(pk_[0]), "+v"(pk_[2]));
            asm("v_permlane32_swap_b32 %0, %1" : "+v"(pk_[1]), "+v"(pk_[3]));
            asm("v_permlane32_swap_b32 %0, %1" : "+v"(pk_[4]), "+v"(pk_[6]));
            asm("v_permlane32_swap_b32 %0, %1" : "+v"(pk_[5]), "+v"(pk_[7]));
            uint4 u0 = {pk_[0], pk_[1], pk_[2], pk_[3]};
            uint4 u1 = {pk_[4], pk_[5], pk_[6], pk_[7]};
            short8 pa0 = __builtin_bit_cast(short8, u0);
            short8 pa1 = __builtin_bit_cast(short8, u1);
            const unsigned short* vp = Vf + ((size_t)((bh * 16 + ktg) * 2 + ks) * 2) * 512 + lane * 8;
            short8 vf0 = *(const short8*)(vp);
            short8 vf1 = *(const short8*)(vp + 512);
            accO = __builtin_amdgcn_mfma_f32_32x32x16_bf16(asbf(pa0), asbf(vf0), accO, 0, 0, 0);
            accO = __builtin_amdgcn_mfma_f32_32x32x16_bf16(asbf(pa1), asbf(vf1), accO, 0, 0, 0);
        }
        // single-buffer update: wait all reads, write next tile, wait writes
        if (kt < 7) {
            __syncthreads();
#pragma unroll
            for (int p = 0; p < 4; p++) {
                uint4 o = {gg[p][0], gg[p][1], gg[p][2], gg[p][3]};
                *(uint4*)&posb[p][gq][gk] = o;
            }
            __syncthreads();
        }
    }

    // epilogue
    {
        size_t base = ((size_t)((b * 2 + kc) * 16 + head)) << 10;
#pragma unroll
        for (int r = 0; r < 16; r++) {
            int qrow = (r & 3) + 8 * (r >> 2) + 4 * hi;
            partial[(base + q0 + qrow) * 32 + q5] = accO[r];
        }
        if (hi == 0) {
            ml[(base + q0 + q5) * 2 + 0] = m_run;
            ml[(base + q0 + q5) * 2 + 1] = l_run;
            if (kc == 0)
                lbuf[(((size_t)((b << 4) + head)) << 10) + q0 + q5] = lb_;
        }
    }
}

// ---------------- combine partials + blank (x4 vectorized) ----------------
__global__ __launch_bounds__(256) void k_comb(const float* __restrict__ partial,
                                              const float* __restrict__ ml,
                                              const float* __restrict__ lbuf,
                                              const float* __restrict__ blank_v,
                                              unsigned short* __restrict__ attnO) {
    int t = blockIdx.x * 256 + threadIdx.x;     // 524288 threads
    int d4 = (t & 7) * 4;
    int row = t >> 3;                            // (b*16+h)*1024 + q
    int b = row >> 14, h = (row >> 10) & 15, q = row & 1023;
    size_t iA = ((size_t)((b * 2 + 0) * 16 + h) << 10) + q;
    size_t iB = ((size_t)((b * 2 + 1) * 16 + h) << 10) + q;
    float mA = ml[iA * 2], lA = ml[iA * 2 + 1];
    float mB = ml[iB * 2], lB = ml[iB * 2 + 1];
    float lb = lbuf[row];
    float M = fmaxf(mA, mB);
    float eA = __expf(mA - M), eB = __expf(mB - M);
    float L = lA * eA + lB * eB;
    float invL = 1.0f / L;
    float bw = __expf(lb - M) * invL;
    float4 pA = *(const float4*)&partial[iA * 32 + d4];
    float4 pB = *(const float4*)&partial[iB * 32 + d4];
    float4 bv = *(const float4*)&blank_v[h * 32 + d4];
    unsigned short o[4];
    o[0] = f2bf((pA.x * eA + pB.x * eB) * invL + bw * bv.x);
    o[1] = f2bf((pA.y * eA + pB.y * eB) * invL + bw * bv.y);
    o[2] = f2bf((pA.z * eA + pB.z * eB) * invL + bw * bv.z);
    o[3] = f2bf((pA.w * eA + pB.w * eB) * invL + bw * bv.w);
    *(uint2*)&attnO[((size_t)((b << 10) + q)) * 512 + h * 32 + d4] = *(uint2*)o;
}

// ---------------- final projection GEMM ----------------
__global__ __launch_bounds__(256) void k_proj(const unsigned short* __restrict__ A,
                                              const unsigned short* __restrict__ Bw,
                                              const float* __restrict__ bias,
                                              float* __restrict__ out) {
    __shared__ __align__(16) unsigned short As[128][72];
    __shared__ __align__(16) unsigned short Bs[64][72];
    int tid = threadIdx.x, lane = tid & 63, wid = tid >> 6;
    int m0 = blockIdx.y * 128, n0 = blockIdx.x * 64;
    int wm = wid >> 1, wn = wid & 1;
    f32x4 acc[4][2] = {};

    for (int k0 = 0; k0 < 512; k0 += 64) {
        {
            int row = tid >> 1, cs = (tid & 1) * 32;
            const short8* src = (const short8*)(A + (size_t)(m0 + row) * 512 + k0 + cs);
            short8* dst = (short8*)(&As[row][cs]);
            dst[0] = src[0]; dst[1] = src[1]; dst[2] = src[2]; dst[3] = src[3];
        }
        {
            int row = tid >> 2, cs = (tid & 3) * 16;
            const short8* src = (const short8*)(Bw + (size_t)(n0 + row) * 512 + k0 + cs);
            short8* dst = (short8*)(&Bs[row][cs]);
            dst[0] = src[0]; dst[1] = src[1];
        }
        __syncthreads();
#pragma unroll
        for (int kk = 0; kk < 64; kk += 32) {
            short8 a[4], b[2];
#pragma unroll
            for (int m = 0; m < 4; m++)
                a[m] = *(const short8*)(&As[wm * 64 + m * 16 + (lane & 15)][kk + ((lane >> 4) << 3)]);
#pragma unroll
            for (int n = 0; n < 2; n++)
                b[n] = *(const short8*)(&Bs[wn * 32 + n * 16 + (lane & 15)][kk + ((lane >> 4) << 3)]);
#pragma unroll
            for (int m = 0; m < 4; m++) {
#pragma unroll
                for (int n = 0; n < 2; n++)
                    acc[m][n] = __builtin_amdgcn_mfma_f32_16x16x32_bf16(asbf(a[m]), asbf(b[n]), acc[m][n], 0, 0, 0);
            }
        }
        __syncthreads();
    }
#pragma unroll
    for (int m = 0; m < 4; m++) {
#pragma unroll
        for (int n = 0; n < 2; n++) {
            int col = n0 + wn * 32 + n * 16 + (lane & 15);
            float bv = bias[col];
#pragma unroll
            for (int r = 0; r < 4; r++) {
                int row = m0 + wm * 64 + m * 16 + ((lane >> 4) << 2) + r;
                out[(size_t)row * 512 + col] = acc[m][n][r] + bv;
            }
        }
    }
}

extern "C" void kernel_launch(void* const* d_in, const int* in_sizes, int n_in,
                              void* d_out, int out_size, void* d_ws, size_t ws_size,
                              hipStream_t stream) {
    const float* feat    = (const float*)d_in[0];
    const int*   pe_idx  = (const int*)d_in[3];
    const float* pret    = (const float*)d_in[5];
    const float* qw      = (const float*)d_in[6];
    const float* qb      = (const float*)d_in[7];
    const float* kvw     = (const float*)d_in[8];
    const float* kvb     = (const float*)d_in[9];
    const float* pew     = (const float*)d_in[10];
    const float* peb     = (const float*)d_in[11];
    const float* blank_k = (const float*)d_in[12];
    const float* blank_v = (const float*)d_in[13];
    const float* projw   = (const float*)d_in[14];
    const float* projb   = (const float*)d_in[15];

    char* ws = (char*)d_ws;
    unsigned short* featb  = (unsigned short*)(ws);                  // 4 MB (reused as attnO)
    unsigned short* wqkv   = (unsigned short*)(ws + 4194304);        // 1.5 MB
    unsigned short* projwb = (unsigned short*)(ws + 5767168);        // 0.5 MB
    float*          bqkv   = (float*)(ws + 6291456);                 // 6 KB
    unsigned short* peAll  = (unsigned short*)(ws + 6297600);        // 128 KB
    unsigned short* Qf     = (unsigned short*)(ws + 6428672);        // 4 MB
    unsigned short* Kf     = (unsigned short*)(ws + 10622976);       // 4 MB
    unsigned short* Vf     = (unsigned short*)(ws + 14817280);       // 4 MB
    float*          partial= (float*)(ws + 19011584);                // 16 MB
    float*          mlb    = (float*)(ws + 35788800);                // 1 MB
    float*          lbuf   = (float*)(ws + 36837376);                // 256 KB
    unsigned short* attnO  = featb;                                  // alias (featb dead after k_qkv)

    k_prep<<<dim3(5382), dim3(256), 0, stream>>>(feat, qw, qb, kvw, kvb, pew, peb, pret, projw,
                                                 featb, wqkv, bqkv, projwb, peAll);
    k_qkv<<<dim3(12, 32), dim3(512), 0, stream>>>(featb, wqkv, bqkv, Qf, Kf, Vf);
    k_attn<<<dim3(512), dim3(512), 0, stream>>>(Qf, Kf, Vf, pe_idx, peAll, blank_k,
                                                partial, mlb, lbuf);
    k_comb<<<dim3(2048), dim3(256), 0, stream>>>(partial, mlb, lbuf, blank_v, attnO);
    k_proj<<<dim3(8, 32), dim3(256), 0, stream>>>(attnO, projwb, projb, (float*)d_out);
}

// Round 8
// 88.716 us; speedup vs baseline: 1.0547x; 1.0547x over previous
//
#include <hip/hip_runtime.h>
#include <hip/hip_fp16.h>

typedef __attribute__((ext_vector_type(8))) short short8;
typedef __attribute__((ext_vector_type(8))) __bf16 bf16x8;
typedef __attribute__((ext_vector_type(4))) float f32x4;
typedef __attribute__((ext_vector_type(16))) float f32x16;

#define DEV __device__ __forceinline__

DEV unsigned short f2bf(float f) {
    unsigned int u = __float_as_uint(f);
    return (unsigned short)((u + 0x7FFFu + ((u >> 16) & 1u)) >> 16);
}
DEV float bf2f(unsigned short s) { return __uint_as_float(((unsigned int)s) << 16); }
DEV bf16x8 asbf(short8 v) { return __builtin_bit_cast(bf16x8, v); }

// ---------------- prep kernel (feat cast + weight pack fused) ----------------
__global__ __launch_bounds__(256) void k_prep(const float* __restrict__ feat,
                                              const float* __restrict__ qw, const float* __restrict__ qb,
                                              const float* __restrict__ kvw, const float* __restrict__ kvb,
                                              const float* __restrict__ pew, const float* __restrict__ peb,
                                              const float* __restrict__ pret, const float* __restrict__ projw,
                                              unsigned short* __restrict__ featb,
                                              unsigned short* __restrict__ wqkv, float* __restrict__ bqkv,
                                              unsigned short* __restrict__ projwb, unsigned short* __restrict__ peAll) {
    const float scale = 0.17677669529663687f; // 1/sqrt(32)
    int i0 = blockIdx.x * 256 + threadIdx.x;
    if (i0 < 262144) {                        // feat f32 -> bf16, 8/thread
        const float4* f4 = (const float4*)feat + (size_t)i0 * 2;
        float4 a = f4[0], c = f4[1];
        short8 o;
        o[0] = (short)f2bf(a.x); o[1] = (short)f2bf(a.y);
        o[2] = (short)f2bf(a.z); o[3] = (short)f2bf(a.w);
        o[4] = (short)f2bf(c.x); o[5] = (short)f2bf(c.y);
        o[6] = (short)f2bf(c.z); o[7] = (short)f2bf(c.w);
        ((short8*)featb)[i0] = o;
        return;
    }
    int i = i0 - 262144;
    if (i < 786432) {                         // wqkv [1536][512]
        int o = i >> 9, k = i & 511;
        float v = (o < 512) ? qw[(o << 9) + k] * scale : kvw[((o - 512) << 9) + k];
        wqkv[i] = f2bf(v);
    } else if (i < 786432 + 262144) {
        int j = i - 786432;
        projwb[j] = f2bf(projw[j]);
    } else if (i < 786432 + 262144 + 1536) {
        int o = i - (786432 + 262144);
        bqkv[o] = (o < 512) ? qb[o] * scale : kvb[o - 512];
    } else if (i < 786432 + 262144 + 1536 + 65536) { // peAll[t][16] f16
        int j = i - (786432 + 262144 + 1536);
        int t = j >> 4, h = j & 15;
        float s = peb[h];
#pragma unroll
        for (int u = 0; u < 5; u++) s += pret[t * 5 + u] * pew[h * 5 + u];
        peAll[j] = __builtin_bit_cast(unsigned short, __float2half(s));
    }
}

// ---------------- QKV GEMM: 128x128 tile, 512 threads (epilogue scatters frag order) ----------------
__global__ __launch_bounds__(512, 2) void k_qkv(const unsigned short* __restrict__ A,
                                                const unsigned short* __restrict__ Bw,
                                                const float* __restrict__ bias,
                                                unsigned short* __restrict__ Qf,
                                                unsigned short* __restrict__ Kf,
                                                unsigned short* __restrict__ Vf) {
    __shared__ __align__(16) unsigned short As[128][72];
    __shared__ __align__(16) unsigned short Bs[128][72];
    int tid = threadIdx.x, lane = tid & 63, wid = tid >> 6;
    int m0 = blockIdx.y * 128, n0 = blockIdx.x * 128;
    int wm = wid & 3, wn = wid >> 2;
    f32x4 acc[2][4] = {};

    for (int k0 = 0; k0 < 512; k0 += 64) {
        {
            int row = tid >> 2, cs = (tid & 3) * 16;
            const short8* srcA = (const short8*)(A + (size_t)(m0 + row) * 512 + k0 + cs);
            short8* dstA = (short8*)(&As[row][cs]);
            dstA[0] = srcA[0]; dstA[1] = srcA[1];
            const short8* srcB = (const short8*)(Bw + (size_t)(n0 + row) * 512 + k0 + cs);
            short8* dstB = (short8*)(&Bs[row][cs]);
            dstB[0] = srcB[0]; dstB[1] = srcB[1];
        }
        __syncthreads();
#pragma unroll
        for (int kk = 0; kk < 64; kk += 32) {
            short8 a[2], b[4];
#pragma unroll
            for (int m = 0; m < 2; m++)
                a[m] = *(const short8*)(&As[wm * 32 + m * 16 + (lane & 15)][kk + ((lane >> 4) << 3)]);
#pragma unroll
            for (int n = 0; n < 4; n++)
                b[n] = *(const short8*)(&Bs[wn * 64 + n * 16 + (lane & 15)][kk + ((lane >> 4) << 3)]);
#pragma unroll
            for (int m = 0; m < 2; m++) {
#pragma unroll
                for (int n = 0; n < 4; n++)
                    acc[m][n] = __builtin_amdgcn_mfma_f32_16x16x32_bf16(asbf(a[m]), asbf(b[n]), acc[m][n], 0, 0, 0);
            }
        }
        __syncthreads();
    }
#pragma unroll
    for (int m = 0; m < 2; m++) {
#pragma unroll
        for (int n = 0; n < 4; n++) {
            int col = n0 + wn * 64 + n * 16 + (lane & 15);
            float bv = bias[col];
#pragma unroll
            for (int r = 0; r < 4; r++) {
                int row = m0 + wm * 32 + m * 16 + ((lane >> 4) << 2) + r;
                float v = acc[m][n][r] + bv;
                unsigned short bb = f2bf(v);
                int batch = row >> 10, nn = row & 1023;
                if (col < 512) {            // Q
                    int h = col >> 5, d = col & 31;
                    int bh = (batch << 4) + h;
                    int qt = nn >> 5, q5 = nn & 31;
                    int sub = d >> 4, hi2 = (d >> 3) & 1, j = d & 7;
                    Qf[((((size_t)(bh * 32 + qt) * 2 + sub) * 64) + hi2 * 32 + q5) * 8 + j] = bb;
                } else {
                    int oo = col - 512, h = oo >> 6, rem = oo & 63;
                    int bh = (batch << 4) + h;
                    int kt = nn >> 6, ks = (nn >> 5) & 1;
                    if (rem < 32) {         // K
                        int d = rem, half = d >> 4, hi2 = (d >> 3) & 1, j = d & 7, q5 = nn & 31;
                        Kf[((((size_t)((bh * 16 + kt) * 2 + ks) * 2 + half) * 64) + hi2 * 32 + q5) * 8 + j] = bb;
                    } else {                // V
                        int d = rem - 32, nb = nn & 31;
                        int half = nb >> 4, hi2 = (nb >> 3) & 1, j = nb & 7;
                        Vf[((((size_t)((bh * 16 + kt) * 2 + ks) * 2 + half) * 64) + hi2 * 32 + d) * 8 + j] = bb;
                    }
                }
            }
        }
    }
}

// ---------------- fused attention: LDS-resident pe table, ds-gather pos ----------------
// grid 512: b=bid&3, qt=(bid>>2)&31, kc=(bid>>7)&1, hg=bid>>8
// 512 threads = 8 waves; wave w -> head hg*8+w; q-tile 32; k-chunk 512 in 8 tiles of 64
__global__ __launch_bounds__(512, 4) void k_attn(const unsigned short* __restrict__ Qf,
                                                 const unsigned short* __restrict__ Kf,
                                                 const unsigned short* __restrict__ Vf,
                                                 const int* __restrict__ pe_idx,
                                                 const unsigned short* __restrict__ peAll,
                                                 const float* __restrict__ blank_k,
                                                 float* __restrict__ partial,
                                                 float* __restrict__ ml,
                                                 float* __restrict__ lbuf) {
    __shared__ __align__(16) unsigned short peT8[4096][8];   // 64 KB: this hg's 8 heads, f16
    __shared__ int idxT[64][33];                             // 8.25 KB transposed idx tile [k][q]

    int tid = threadIdx.x, lane = tid & 63, w = tid >> 6;
    int q5 = lane & 31, hi = lane >> 5;
    int bid = blockIdx.x;
    int b = bid & 3, qt = (bid >> 2) & 31, kc = (bid >> 7) & 1, hg = bid >> 8;
    int q0 = qt * 32;
    int head = hg * 8 + w, bh = (b << 4) + head;
    int dwsel = w >> 1, halfsel = w & 1;    // dword (pair of heads) within peT8 row

    // stage peT8 (one-time): thread t loads rows t, t+512, ... (16B each)
#pragma unroll
    for (int j = 0; j < 8; j++) {
        int r = j * 512 + tid;
        *(uint4*)&peT8[r][0] = *(const uint4*)(peAll + (size_t)r * 16 + hg * 8);
    }

    // idx staging map: thread -> (q row, 4 consecutive k), write transposed
    int sq = tid >> 4, sk = (tid & 15) * 4;
    const int* pib = pe_idx + ((size_t)((b << 10) + q0 + sq)) * 1024 + kc * 512 + sk;

    short8 qf[2];
    float lb_, m_run, l_run;
    f32x16 accO = {};
    const f32x16 zero16 = {};

    {
        const unsigned short* qb_ = Qf + ((size_t)(bh * 32 + qt) * 2) * 512 + lane * 8;
        qf[0] = *(const short8*)(qb_);
        qf[1] = *(const short8*)(qb_ + 512);
        float dot = 0.f;
#pragma unroll
        for (int sub = 0; sub < 2; sub++) {
            const float* bk = blank_k + head * 32 + sub * 16 + hi * 8;
#pragma unroll
            for (int t = 0; t < 8; t++) dot += bf2f((unsigned short)qf[sub][t]) * bk[t];
        }
        dot += __shfl_xor(dot, 32, 64);
        lb_ = dot;
        m_run = (kc == 0) ? dot : -1e30f;
        l_run = (kc == 0) ? 1.0f : 0.0f;
    }

    // prologue: stage idx tile 0 (transposed)
    {
        int4 i4 = *(const int4*)(pib);
        idxT[sk + 0][sq] = i4.x;
        idxT[sk + 1][sq] = i4.y;
        idxT[sk + 2][sq] = i4.z;
        idxT[sk + 3][sq] = i4.w;
    }
    __syncthreads();   // peT8 + idxT ready

    for (int kt = 0; kt < 8; kt++) {
        int ktg = kc * 8 + kt;
        // S^T = K x Q^T (32k x 32q), rows k=(r&3)+8*(r>>2)+4*hi, col q=q5
        f32x16 st[2];
#pragma unroll
        for (int ks = 0; ks < 2; ks++) {
            const unsigned short* kp = Kf + ((size_t)((bh * 16 + ktg) * 2 + ks) * 2) * 512 + lane * 8;
            short8 kf0 = *(const short8*)(kp);
            short8 kf1 = *(const short8*)(kp + 512);
            st[ks] = __builtin_amdgcn_mfma_f32_32x32x16_bf16(asbf(kf0), asbf(qf[0]), zero16, 0, 0, 0);
            st[ks] = __builtin_amdgcn_mfma_f32_32x32x16_bf16(asbf(kf1), asbf(qf[1]), st[ks], 0, 0, 0);
        }
        // pos add via LDS gathers: idxT[k][q5] -> peT8[idx] dword dwsel
#pragma unroll
        for (int ks = 0; ks < 2; ks++) {
#pragma unroll
            for (int r = 0; r < 16; r++) {
                int kl = (r & 3) + 8 * (r >> 2) + 4 * hi + 32 * ks;
                int idx = idxT[kl][q5];
                unsigned pd = *(const unsigned*)&peT8[idx][dwsel * 2];
                __half2 h2 = __builtin_bit_cast(__half2, pd);
                st[ks][r] += halfsel ? __high2float(h2) : __low2float(h2);
            }
        }
        // prefetch next idx tile into regs (VMEM latency hidden under softmax+PV)
        int4 nxt;
        if (kt < 7) nxt = *(const int4*)(pib + (kt + 1) * 64);

        // tile max: tree reduction
        float tm[16];
#pragma unroll
        for (int i = 0; i < 16; i++) tm[i] = fmaxf(st[0][i], st[1][i]);
#pragma unroll
        for (int i = 0; i < 8; i++) tm[i] = fmaxf(tm[i], tm[i + 8]);
#pragma unroll
        for (int i = 0; i < 4; i++) tm[i] = fmaxf(tm[i], tm[i + 4]);
        float mx = fmaxf(fmaxf(tm[0], tm[1]), fmaxf(tm[2], tm[3]));
        mx = fmaxf(mx, __shfl_xor(mx, 32, 64));
        // defer-max (T13)
        if (!__all(mx <= m_run + 8.0f)) {
            float mn = fmaxf(m_run, mx);
            float fac = __expf(m_run - mn);
            m_run = mn;
            l_run *= fac;
#pragma unroll
            for (int r = 0; r < 16; r++) {
                int qrow = (r & 3) + 8 * (r >> 2) + 4 * hi;
                float facr = __shfl(fac, qrow, 64);
                accO[r] *= facr;
            }
        }
#pragma unroll
        for (int ks = 0; ks < 2; ks++)
#pragma unroll
            for (int r = 0; r < 16; r++)
                st[ks][r] = __expf(st[ks][r] - m_run);
        // sum: tree reduction
        float ts[16];
#pragma unroll
        for (int i = 0; i < 16; i++) ts[i] = st[0][i] + st[1][i];
#pragma unroll
        for (int i = 0; i < 8; i++) ts[i] += ts[i + 8];
#pragma unroll
        for (int i = 0; i < 4; i++) ts[i] += ts[i + 4];
        float sum = (ts[0] + ts[1]) + (ts[2] + ts[3]);
        sum += __shfl_xor(sum, 32, 64);
        l_run += sum;
        // P -> A-frag via v_cvt_pk_bf16_f32 + permlane32_swap (T12), then PV
#pragma unroll
        for (int ks = 0; ks < 2; ks++) {
            unsigned pk_[8];
#pragma unroll
            for (int i = 0; i < 8; i++) {
                float plo = st[ks][2 * i], phi = st[ks][2 * i + 1];
                asm("v_cvt_pk_bf16_f32 %0, %1, %2" : "=v"(pk_[i]) : "v"(plo), "v"(phi));
            }
            asm("v_permlane32_swap_b32 %0, %1" : "+v"(pk_[0]), "+v"(pk_[2]));
            asm("v_permlane32_swap_b32 %0, %1" : "+v"(pk_[1]), "+v"(pk_[3]));
            asm("v_permlane32_swap_b32 %0, %1" : "+v"(pk_[4]), "+v"(pk_[6]));
            asm("v_permlane32_swap_b32 %0, %1" : "+v"(pk_[5]), "+v"(pk_[7]));
            uint4 u0 = {pk_[0], pk_[1], pk_[2], pk_[3]};
            uint4 u1 = {pk_[4], pk_[5], pk_[6], pk_[7]};
            short8 pa0 = __builtin_bit_cast(short8, u0);
            short8 pa1 = __builtin_bit_cast(short8, u1);
            const unsigned short* vp = Vf + ((size_t)((bh * 16 + ktg) * 2 + ks) * 2) * 512 + lane * 8;
            short8 vf0 = *(const short8*)(vp);
            short8 vf1 = *(const short8*)(vp + 512);
            accO = __builtin_amdgcn_mfma_f32_32x32x16_bf16(asbf(pa0), asbf(vf0), accO, 0, 0, 0);
            accO = __builtin_amdgcn_mfma_f32_32x32x16_bf16(asbf(pa1), asbf(vf1), accO, 0, 0, 0);
        }
        // single-buffered idxT swap: wait readers, write next tile, wait writers
        if (kt < 7) {
            __syncthreads();
            idxT[sk + 0][sq] = nxt.x;
            idxT[sk + 1][sq] = nxt.y;
            idxT[sk + 2][sq] = nxt.z;
            idxT[sk + 3][sq] = nxt.w;
            __syncthreads();
        }
    }

    // epilogue
    {
        size_t base = ((size_t)((b * 2 + kc) * 16 + head)) << 10;
#pragma unroll
        for (int r = 0; r < 16; r++) {
            int qrow = (r & 3) + 8 * (r >> 2) + 4 * hi;
            partial[(base + q0 + qrow) * 32 + q5] = accO[r];
        }
        if (hi == 0) {
            ml[(base + q0 + q5) * 2 + 0] = m_run;
            ml[(base + q0 + q5) * 2 + 1] = l_run;
            if (kc == 0)
                lbuf[(((size_t)((b << 4) + head)) << 10) + q0 + q5] = lb_;
        }
    }
}

// ---------------- combine partials + blank (x4 vectorized) ----------------
__global__ __launch_bounds__(256) void k_comb(const float* __restrict__ partial,
                                              const float* __restrict__ ml,
                                              const float* __restrict__ lbuf,
                                              const float* __restrict__ blank_v,
                                              unsigned short* __restrict__ attnO) {
    int t = blockIdx.x * 256 + threadIdx.x;     // 524288 threads
    int d4 = (t & 7) * 4;
    int row = t >> 3;                            // (b*16+h)*1024 + q
    int b = row >> 14, h = (row >> 10) & 15, q = row & 1023;
    size_t iA = ((size_t)((b * 2 + 0) * 16 + h) << 10) + q;
    size_t iB = ((size_t)((b * 2 + 1) * 16 + h) << 10) + q;
    float mA = ml[iA * 2], lA = ml[iA * 2 + 1];
    float mB = ml[iB * 2], lB = ml[iB * 2 + 1];
    float lb = lbuf[row];
    float M = fmaxf(mA, mB);
    float eA = __expf(mA - M), eB = __expf(mB - M);
    float L = lA * eA + lB * eB;
    float invL = 1.0f / L;
    float bw = __expf(lb - M) * invL;
    float4 pA = *(const float4*)&partial[iA * 32 + d4];
    float4 pB = *(const float4*)&partial[iB * 32 + d4];
    float4 bv = *(const float4*)&blank_v[h * 32 + d4];
    unsigned short o[4];
    o[0] = f2bf((pA.x * eA + pB.x * eB) * invL + bw * bv.x);
    o[1] = f2bf((pA.y * eA + pB.y * eB) * invL + bw * bv.y);
    o[2] = f2bf((pA.z * eA + pB.z * eB) * invL + bw * bv.z);
    o[3] = f2bf((pA.w * eA + pB.w * eB) * invL + bw * bv.w);
    *(uint2*)&attnO[((size_t)((b << 10) + q)) * 512 + h * 32 + d4] = *(uint2*)o;
}

// ---------------- final projection GEMM ----------------
__global__ __launch_bounds__(256) void k_proj(const unsigned short* __restrict__ A,
                                              const unsigned short* __restrict__ Bw,
                                              const float* __restrict__ bias,
                                              float* __restrict__ out) {
    __shared__ __align__(16) unsigned short As[128][72];
    __shared__ __align__(16) unsigned short Bs[64][72];
    int tid = threadIdx.x, lane = tid & 63, wid = tid >> 6;
    int m0 = blockIdx.y * 128, n0 = blockIdx.x * 64;
    int wm = wid >> 1, wn = wid & 1;
    f32x4 acc[4][2] = {};

    for (int k0 = 0; k0 < 512; k0 += 64) {
        {
            int row = tid >> 1, cs = (tid & 1) * 32;
            const short8* src = (const short8*)(A + (size_t)(m0 + row) * 512 + k0 + cs);
            short8* dst = (short8*)(&As[row][cs]);
            dst[0] = src[0]; dst[1] = src[1]; dst[2] = src[2]; dst[3] = src[3];
        }
        {
            int row = tid >> 2, cs = (tid & 3) * 16;
            const short8* src = (const short8*)(Bw + (size_t)(n0 + row) * 512 + k0 + cs);
            short8* dst = (short8*)(&Bs[row][cs]);
            dst[0] = src[0]; dst[1] = src[1];
        }
        __syncthreads();
#pragma unroll
        for (int kk = 0; kk < 64; kk += 32) {
            short8 a[4], b[2];
#pragma unroll
            for (int m = 0; m < 4; m++)
                a[m] = *(const short8*)(&As[wm * 64 + m * 16 + (lane & 15)][kk + ((lane >> 4) << 3)]);
#pragma unroll
            for (int n = 0; n < 2; n++)
                b[n] = *(const short8*)(&Bs[wn * 32 + n * 16 + (lane & 15)][kk + ((lane >> 4) << 3)]);
#pragma unroll
            for (int m = 0; m < 4; m++) {
#pragma unroll
                for (int n = 0; n < 2; n++)
                    acc[m][n] = __builtin_amdgcn_mfma_f32_16x16x32_bf16(asbf(a[m]), asbf(b[n]), acc[m][n], 0, 0, 0);
            }
        }
        __syncthreads();
    }
#pragma unroll
    for (int m = 0; m < 4; m++) {
#pragma unroll
        for (int n = 0; n < 2; n++) {
            int col = n0 + wn * 32 + n * 16 + (lane & 15);
            float bv = bias[col];
#pragma unroll
            for (int r = 0; r < 4; r++) {
                int row = m0 + wm * 64 + m * 16 + ((lane >> 4) << 2) + r;
                out[(size_t)row * 512 + col] = acc[m][n][r] + bv;
            }
        }
    }
}

extern "C" void kernel_launch(void* const* d_in, const int* in_sizes, int n_in,
                              void* d_out, int out_size, void* d_ws, size_t ws_size,
                              hipStream_t stream) {
    const float* feat    = (const float*)d_in[0];
    const int*   pe_idx  = (const int*)d_in[3];
    const float* pret    = (const float*)d_in[5];
    const float* qw      = (const float*)d_in[6];
    const float* qb      = (const float*)d_in[7];
    const float* kvw     = (const float*)d_in[8];
    const float* kvb     = (const float*)d_in[9];
    const float* pew     = (const float*)d_in[10];
    const float* peb     = (const float*)d_in[11];
    const float* blank_k = (const float*)d_in[12];
    const float* blank_v = (const float*)d_in[13];
    const float* projw   = (const float*)d_in[14];
    const float* projb   = (const float*)d_in[15];

    char* ws = (char*)d_ws;
    unsigned short* featb  = (unsigned short*)(ws);                  // 4 MB (reused as attnO)
    unsigned short* wqkv   = (unsigned short*)(ws + 4194304);        // 1.5 MB
    unsigned short* projwb = (unsigned short*)(ws + 5767168);        // 0.5 MB
    float*          bqkv   = (float*)(ws + 6291456);                 // 6 KB
    unsigned short* peAll  = (unsigned short*)(ws + 6297600);        // 128 KB
    unsigned short* Qf     = (unsigned short*)(ws + 6428672);        // 4 MB
    unsigned short* Kf     = (unsigned short*)(ws + 10622976);       // 4 MB
    unsigned short* Vf     = (unsigned short*)(ws + 14817280);       // 4 MB
    float*          partial= (float*)(ws + 19011584);                // 16 MB
    float*          mlb    = (float*)(ws + 35788800);                // 1 MB
    float*          lbuf   = (float*)(ws + 36837376);                // 256 KB
    unsigned short* attnO  = featb;                                  // alias (featb dead after k_qkv)

    k_prep<<<dim3(5382), dim3(256), 0, stream>>>(feat, qw, qb, kvw, kvb, pew, peb, pret, projw,
                                                 featb, wqkv, bqkv, projwb, peAll);
    k_qkv<<<dim3(12, 32), dim3(512), 0, stream>>>(featb, wqkv, bqkv, Qf, Kf, Vf);
    k_attn<<<dim3(512), dim3(512), 0, stream>>>(Qf, Kf, Vf, pe_idx, peAll, blank_k,
                                                partial, mlb, lbuf);
    k_comb<<<dim3(2048), dim3(256), 0, stream>>>(partial, mlb, lbuf, blank_v, attnO);
    k_proj<<<dim3(8, 32), dim3(256), 0, stream>>>(attnO, projwb, projb, (float*)d_out);
}

// Round 10
// 72.538 us; speedup vs baseline: 1.2900x; 1.2230x over previous
//
#include <hip/hip_runtime.h>
#include <hip/hip_fp16.h>

typedef __attribute__((ext_vector_type(8))) short short8;
typedef __attribute__((ext_vector_type(8))) __bf16 bf16x8;
typedef __attribute__((ext_vector_type(4))) float f32x4;
typedef __attribute__((ext_vector_type(16))) float f32x16;

#define DEV __device__ __forceinline__

DEV unsigned short f2bf(float f) {
    unsigned int u = __float_as_uint(f);
    return (unsigned short)((u + 0x7FFFu + ((u >> 16) & 1u)) >> 16);
}
DEV float bf2f(unsigned short s) { return __uint_as_float(((unsigned int)s) << 16); }
DEV bf16x8 asbf(short8 v) { return __builtin_bit_cast(bf16x8, v); }

// ---------------- prep kernel (feat cast + weight pack fused) ----------------
// peG layout: [hg(4)][4096][4] f16  (head h -> group h>>2, slot h&3)
__global__ __launch_bounds__(256) void k_prep(const float* __restrict__ feat,
                                              const float* __restrict__ qw, const float* __restrict__ qb,
                                              const float* __restrict__ kvw, const float* __restrict__ kvb,
                                              const float* __restrict__ pew, const float* __restrict__ peb,
                                              const float* __restrict__ pret, const float* __restrict__ projw,
                                              unsigned short* __restrict__ featb,
                                              unsigned short* __restrict__ wqkv, float* __restrict__ bqkv,
                                              unsigned short* __restrict__ projwb, unsigned short* __restrict__ peG) {
    const float scale = 0.17677669529663687f; // 1/sqrt(32)
    int i0 = blockIdx.x * 256 + threadIdx.x;
    if (i0 < 262144) {                        // feat f32 -> bf16, 8/thread
        const float4* f4 = (const float4*)feat + (size_t)i0 * 2;
        float4 a = f4[0], c = f4[1];
        short8 o;
        o[0] = (short)f2bf(a.x); o[1] = (short)f2bf(a.y);
        o[2] = (short)f2bf(a.z); o[3] = (short)f2bf(a.w);
        o[4] = (short)f2bf(c.x); o[5] = (short)f2bf(c.y);
        o[6] = (short)f2bf(c.z); o[7] = (short)f2bf(c.w);
        ((short8*)featb)[i0] = o;
        return;
    }
    int i = i0 - 262144;
    if (i < 786432) {                         // wqkv [1536][512]
        int o = i >> 9, k = i & 511;
        float v = (o < 512) ? qw[(o << 9) + k] * scale : kvw[((o - 512) << 9) + k];
        wqkv[i] = f2bf(v);
    } else if (i < 786432 + 262144) {
        int j = i - 786432;
        projwb[j] = f2bf(projw[j]);
    } else if (i < 786432 + 262144 + 1536) {
        int o = i - (786432 + 262144);
        bqkv[o] = (o < 512) ? qb[o] * scale : kvb[o - 512];
    } else if (i < 786432 + 262144 + 1536 + 65536) { // peG[h>>2][t][h&3] f16
        int j = i - (786432 + 262144 + 1536);
        int t = j >> 4, h = j & 15;
        float s = peb[h];
#pragma unroll
        for (int u = 0; u < 5; u++) s += pret[t * 5 + u] * pew[h * 5 + u];
        peG[(size_t)(h >> 2) * 16384 + t * 4 + (h & 3)] =
            __builtin_bit_cast(unsigned short, __float2half(s));
    }
}

// ---------------- QKV GEMM: 128x64 tile, 256 threads, grid (24,32)=768 (3/CU exact) ----------------
__global__ __launch_bounds__(256) void k_qkv(const unsigned short* __restrict__ A,
                                             const unsigned short* __restrict__ Bw,
                                             const float* __restrict__ bias,
                                             unsigned short* __restrict__ Qf,
                                             unsigned short* __restrict__ Kf,
                                             unsigned short* __restrict__ Vf) {
    __shared__ __align__(16) unsigned short As[128][72];
    __shared__ __align__(16) unsigned short Bs[64][72];
    int tid = threadIdx.x, lane = tid & 63, wid = tid >> 6;
    int m0 = blockIdx.y * 128, n0 = blockIdx.x * 64;
    int wm = wid >> 1, wn = wid & 1;
    f32x4 acc[4][2] = {};

    for (int k0 = 0; k0 < 512; k0 += 64) {
        {
            int row = tid >> 1, cs = (tid & 1) * 32;
            const short8* src = (const short8*)(A + (size_t)(m0 + row) * 512 + k0 + cs);
            short8* dst = (short8*)(&As[row][cs]);
            dst[0] = src[0]; dst[1] = src[1]; dst[2] = src[2]; dst[3] = src[3];
        }
        {
            int row = tid >> 2, cs = (tid & 3) * 16;
            const short8* src = (const short8*)(Bw + (size_t)(n0 + row) * 512 + k0 + cs);
            short8* dst = (short8*)(&Bs[row][cs]);
            dst[0] = src[0]; dst[1] = src[1];
        }
        __syncthreads();
#pragma unroll
        for (int kk = 0; kk < 64; kk += 32) {
            short8 a[4], b[2];
#pragma unroll
            for (int m = 0; m < 4; m++)
                a[m] = *(const short8*)(&As[wm * 64 + m * 16 + (lane & 15)][kk + ((lane >> 4) << 3)]);
#pragma unroll
            for (int n = 0; n < 2; n++)
                b[n] = *(const short8*)(&Bs[wn * 32 + n * 16 + (lane & 15)][kk + ((lane >> 4) << 3)]);
#pragma unroll
            for (int m = 0; m < 4; m++) {
#pragma unroll
                for (int n = 0; n < 2; n++)
                    acc[m][n] = __builtin_amdgcn_mfma_f32_16x16x32_bf16(asbf(a[m]), asbf(b[n]), acc[m][n], 0, 0, 0);
            }
        }
        __syncthreads();
    }
#pragma unroll
    for (int m = 0; m < 4; m++) {
#pragma unroll
        for (int n = 0; n < 2; n++) {
            int col = n0 + wn * 32 + n * 16 + (lane & 15);
            float bv = bias[col];
#pragma unroll
            for (int r = 0; r < 4; r++) {
                int row = m0 + wm * 64 + m * 16 + ((lane >> 4) << 2) + r;
                float v = acc[m][n][r] + bv;
                unsigned short bb = f2bf(v);
                int batch = row >> 10, nn = row & 1023;
                if (col < 512) {            // Q
                    int h = col >> 5, d = col & 31;
                    int bh = (batch << 4) + h;
                    int qt = nn >> 5, q5 = nn & 31;
                    int sub = d >> 4, hi2 = (d >> 3) & 1, j = d & 7;
                    Qf[((((size_t)(bh * 32 + qt) * 2 + sub) * 64) + hi2 * 32 + q5) * 8 + j] = bb;
                } else {
                    int oo = col - 512, h = oo >> 6, rem = oo & 63;
                    int bh = (batch << 4) + h;
                    int kt = nn >> 6, ks = (nn >> 5) & 1;
                    if (rem < 32) {         // K
                        int d = rem, half = d >> 4, hi2 = (d >> 3) & 1, j = d & 7, q5 = nn & 31;
                        Kf[((((size_t)((bh * 16 + kt) * 2 + ks) * 2 + half) * 64) + hi2 * 32 + q5) * 8 + j] = bb;
                    } else {                // V
                        int d = rem - 32, nb = nn & 31;
                        int half = nb >> 4, hi2 = (nb >> 3) & 1, j = nb & 7;
                        Vf[((((size_t)((bh * 16 + kt) * 2 + ks) * 2 + half) * 64) + hi2 * 32 + d) * 8 + j] = bb;
                    }
                }
            }
        }
    }
}

// ---------------- fused attention: 4 heads/block, conflict-free staged pos, no split-k ----------------
// grid 512: b=bid&3, qt=(bid>>2)&31, hg=bid>>7 (0..3)
// 256 threads = 4 waves; wave w -> head hg*4+w; q-tile 32; full k=1024 in 16 tiles of 64
__global__ __launch_bounds__(256, 2) void k_attn(const unsigned short* __restrict__ Qf,
                                                 const unsigned short* __restrict__ Kf,
                                                 const unsigned short* __restrict__ Vf,
                                                 const int* __restrict__ pe_idx,
                                                 const unsigned short* __restrict__ peG,
                                                 const float* __restrict__ blank_k,
                                                 const float* __restrict__ blank_v,
                                                 unsigned short* __restrict__ attnO) {
    __shared__ __align__(8) unsigned short peT4[4096][4];  // 32 KB: this hg's 4 heads, f16
    __shared__ int idxT[64][33];                           // 8.45 KB transposed idx tile [k][q]
    __shared__ unsigned posS[6144];                        // 24 KB: 2048 els x 2 dwords, stride 3

    int tid = threadIdx.x, lane = tid & 63, w = tid >> 6;
    int q5 = lane & 31, hi = lane >> 5;
    int bid = blockIdx.x;
    int b = bid & 3, qt = (bid >> 2) & 31, hg = bid >> 7;
    int q0 = qt * 32;
    int head = hg * 4 + w, bh = (b << 4) + head;
    int dwsel = w >> 1, halfsel = w & 1;

    // stage peT4 (one-time): row r = tid + 256*j2, 8B coalesced from peG
    {
        const unsigned short* pg = peG + (size_t)hg * 16384;
#pragma unroll
        for (int j2 = 0; j2 < 16; j2++) {
            int r = tid + 256 * j2;
            *(uint2*)&peT4[r][0] = *(const uint2*)(pg + r * 4);
        }
    }

    // idx staging map: thread -> (q row sq, 8 consecutive k at sk8)
    int sq = tid >> 3, sk8 = (tid & 7) * 8;
    const int* pib = pe_idx + ((size_t)((b << 10) + q0 + sq)) * 1024 + sk8;

    short8 qf[2];
    float lb_, m_run, l_run;
    f32x16 accO = {};
    const f32x16 zero16 = {};

    {
        const unsigned short* qb_ = Qf + ((size_t)(bh * 32 + qt) * 2) * 512 + lane * 8;
        qf[0] = *(const short8*)(qb_);
        qf[1] = *(const short8*)(qb_ + 512);
        float dot = 0.f;
#pragma unroll
        for (int sub = 0; sub < 2; sub++) {
            const float* bk = blank_k + head * 32 + sub * 16 + hi * 8;
#pragma unroll
            for (int t = 0; t < 8; t++) dot += bf2f((unsigned short)qf[sub][t]) * bk[t];
        }
        dot += __shfl_xor(dot, 32, 64);
        lb_ = dot;
        m_run = dot;
        l_run = 1.0f;
    }

    // prologue: stage idx tile 0 (transposed)
    {
        int4 a0 = *(const int4*)(pib);
        int4 a1 = *(const int4*)(pib + 4);
        idxT[sk8 + 0][sq] = a0.x; idxT[sk8 + 1][sq] = a0.y;
        idxT[sk8 + 2][sq] = a0.z; idxT[sk8 + 3][sq] = a0.w;
        idxT[sk8 + 4][sq] = a1.x; idxT[sk8 + 5][sq] = a1.y;
        idxT[sk8 + 6][sq] = a1.z; idxT[sk8 + 7][sq] = a1.w;
    }
    __syncthreads();   // peT4 + idxT(0) ready

    for (int kt = 0; kt < 16; kt++) {
        // ---- staging phase: gather pos rows once per (q,k), write conflict-free posS ----
#pragma unroll
        for (int j = 0; j < 8; j++) {
            int el = tid + 256 * j;                       // k-local = el>>5, q = el&31
            int idx = idxT[el >> 5][el & 31];
            uint2 pv = *(const uint2*)&peT4[idx][0];
            posS[el * 3 + 0] = pv.x;
            posS[el * 3 + 1] = pv.y;
        }
        __syncthreads();   // posS(kt) ready; idxT(kt) consumed

        // prefetch next idx tile into regs (latency hidden under compute)
        int4 n0_, n1_;
        if (kt < 15) {
            n0_ = *(const int4*)(pib + (kt + 1) * 64);
            n1_ = *(const int4*)(pib + (kt + 1) * 64 + 4);
        }

        // ---- compute phase ----
        // S^T = K x Q^T (32k x 32q), rows k=(r&3)+8*(r>>2)+4*hi, col q=q5
        f32x16 st[2];
#pragma unroll
        for (int ks = 0; ks < 2; ks++) {
            const unsigned short* kp = Kf + ((size_t)((bh * 16 + kt) * 2 + ks) * 2) * 512 + lane * 8;
            short8 kf0 = *(const short8*)(kp);
            short8 kf1 = *(const short8*)(kp + 512);
            st[ks] = __builtin_amdgcn_mfma_f32_32x32x16_bf16(asbf(kf0), asbf(qf[0]), zero16, 0, 0, 0);
            st[ks] = __builtin_amdgcn_mfma_f32_32x32x16_bf16(asbf(kf1), asbf(qf[1]), st[ks], 0, 0, 0);
        }
        // pos add: conflict-free posS reads (bank = (3*q5+dwsel)%32, 2 lanes/bank)
#pragma unroll
        for (int ks = 0; ks < 2; ks++) {
#pragma unroll
            for (int r = 0; r < 16; r++) {
                int kl = (r & 3) + 8 * (r >> 2) + 4 * hi + 32 * ks;
                unsigned pd = posS[(kl * 32 + q5) * 3 + dwsel];
                __half2 h2 = __builtin_bit_cast(__half2, pd);
                st[ks][r] += halfsel ? __high2float(h2) : __low2float(h2);
            }
        }
        // tile max: tree reduction
        float tm[16];
#pragma unroll
        for (int i = 0; i < 16; i++) tm[i] = fmaxf(st[0][i], st[1][i]);
#pragma unroll
        for (int i = 0; i < 8; i++) tm[i] = fmaxf(tm[i], tm[i + 8]);
#pragma unroll
        for (int i = 0; i < 4; i++) tm[i] = fmaxf(tm[i], tm[i + 4]);
        float mx = fmaxf(fmaxf(tm[0], tm[1]), fmaxf(tm[2], tm[3]));
        mx = fmaxf(mx, __shfl_xor(mx, 32, 64));
        // defer-max (T13)
        if (!__all(mx <= m_run + 8.0f)) {
            float mn = fmaxf(m_run, mx);
            float fac = __expf(m_run - mn);
            m_run = mn;
            l_run *= fac;
#pragma unroll
            for (int r = 0; r < 16; r++) {
                int qrow = (r & 3) + 8 * (r >> 2) + 4 * hi;
                float facr = __shfl(fac, qrow, 64);
                accO[r] *= facr;
            }
        }
#pragma unroll
        for (int ks = 0; ks < 2; ks++)
#pragma unroll
            for (int r = 0; r < 16; r++)
                st[ks][r] = __expf(st[ks][r] - m_run);
        // sum: tree reduction
        float ts[16];
#pragma unroll
        for (int i = 0; i < 16; i++) ts[i] = st[0][i] + st[1][i];
#pragma unroll
        for (int i = 0; i < 8; i++) ts[i] += ts[i + 8];
#pragma unroll
        for (int i = 0; i < 4; i++) ts[i] += ts[i + 4];
        float sum = (ts[0] + ts[1]) + (ts[2] + ts[3]);
        sum += __shfl_xor(sum, 32, 64);
        l_run += sum;
        // P -> A-frag via v_cvt_pk_bf16_f32 + permlane32_swap (T12), then PV
#pragma unroll
        for (int ks = 0; ks < 2; ks++) {
            unsigned pk_[8];
#pragma unroll
            for (int i = 0; i < 8; i++) {
                float plo = st[ks][2 * i], phi = st[ks][2 * i + 1];
                asm("v_cvt_pk_bf16_f32 %0, %1, %2" : "=v"(pk_[i]) : "v"(plo), "v"(phi));
            }
            asm("v_permlane32_swap_b32 %0, %1" : "+v"(pk_[0]), "+v"(pk_[2]));
            asm("v_permlane32_swap_b32 %0, %1" : "+v"(pk_[1]), "+v"(pk_[3]));
            asm("v_permlane32_swap_b32 %0, %1" : "+v"(pk_[4]), "+v"(pk_[6]));
            asm("v_permlane32_swap_b32 %0, %1" : "+v"(pk_[5]), "+v"(pk_[7]));
            uint4 u0 = {pk_[0], pk_[1], pk_[2], pk_[3]};
            uint4 u1 = {pk_[4], pk_[5], pk_[6], pk_[7]};
            short8 pa0 = __builtin_bit_cast(short8, u0);
            short8 pa1 = __builtin_bit_cast(short8, u1);
            const unsigned short* vp = Vf + ((size_t)((bh * 16 + kt) * 2 + ks) * 2) * 512 + lane * 8;
            short8 vf0 = *(const short8*)(vp);
            short8 vf1 = *(const short8*)(vp + 512);
            accO = __builtin_amdgcn_mfma_f32_32x32x16_bf16(asbf(pa0), asbf(vf0), accO, 0, 0, 0);
            accO = __builtin_amdgcn_mfma_f32_32x32x16_bf16(asbf(pa1), asbf(vf1), accO, 0, 0, 0);
        }
        // write next idx tile (idxT dead since staging phase; visible after barrier)
        if (kt < 15) {
            idxT[sk8 + 0][sq] = n0_.x; idxT[sk8 + 1][sq] = n0_.y;
            idxT[sk8 + 2][sq] = n0_.z; idxT[sk8 + 3][sq] = n0_.w;
            idxT[sk8 + 4][sq] = n1_.x; idxT[sk8 + 5][sq] = n1_.y;
            idxT[sk8 + 6][sq] = n1_.z; idxT[sk8 + 7][sq] = n1_.w;
        }
        __syncthreads();   // posS consumed; idxT(kt+1) ready
    }

    // epilogue: direct attnO write with blank term.
    // accO[r] is output ROW qrow; l_run/m_run/lb_ live per-lane at q=q5 -> shfl per-row stats.
    {
        float inv = 1.0f / l_run;
        float bw = __expf(lb_ - m_run) * inv;
        float bv = blank_v[head * 32 + q5];
#pragma unroll
        for (int r = 0; r < 16; r++) {
            int qrow = (r & 3) + 8 * (r >> 2) + 4 * hi;
            float inv_r = __shfl(inv, qrow, 64);
            float bw_r = __shfl(bw, qrow, 64);
            float ov = accO[r] * inv_r + bw_r * bv;
            attnO[((size_t)((b << 10) + q0 + qrow)) * 512 + head * 32 + q5] = f2bf(ov);
        }
    }
}

// ---------------- final projection GEMM ----------------
__global__ __launch_bounds__(256) void k_proj(const unsigned short* __restrict__ A,
                                              const unsigned short* __restrict__ Bw,
                                              const float* __restrict__ bias,
                                              float* __restrict__ out) {
    __shared__ __align__(16) unsigned short As[128][72];
    __shared__ __align__(16) unsigned short Bs[64][72];
    int tid = threadIdx.x, lane = tid & 63, wid = tid >> 6;
    int m0 = blockIdx.y * 128, n0 = blockIdx.x * 64;
    int wm = wid >> 1, wn = wid & 1;
    f32x4 acc[4][2] = {};

    for (int k0 = 0; k0 < 512; k0 += 64) {
        {
            int row = tid >> 1, cs = (tid & 1) * 32;
            const short8* src = (const short8*)(A + (size_t)(m0 + row) * 512 + k0 + cs);
            short8* dst = (short8*)(&As[row][cs]);
            dst[0] = src[0]; dst[1] = src[1]; dst[2] = src[2]; dst[3] = src[3];
        }
        {
            int row = tid >> 2, cs = (tid & 3) * 16;
            const short8* src = (const short8*)(Bw + (size_t)(n0 + row) * 512 + k0 + cs);
            short8* dst = (short8*)(&Bs[row][cs]);
            dst[0] = src[0]; dst[1] = src[1];
        }
        __syncthreads();
#pragma unroll
        for (int kk = 0; kk < 64; kk += 32) {
            short8 a[4], b[2];
#pragma unroll
            for (int m = 0; m < 4; m++)
                a[m] = *(const short8*)(&As[wm * 64 + m * 16 + (lane & 15)][kk + ((lane >> 4) << 3)]);
#pragma unroll
            for (int n = 0; n < 2; n++)
                b[n] = *(const short8*)(&Bs[wn * 32 + n * 16 + (lane & 15)][kk + ((lane >> 4) << 3)]);
#pragma unroll
            for (int m = 0; m < 4; m++) {
#pragma unroll
                for (int n = 0; n < 2; n++)
                    acc[m][n] = __builtin_amdgcn_mfma_f32_16x16x32_bf16(asbf(a[m]), asbf(b[n]), acc[m][n], 0, 0, 0);
            }
        }
        __syncthreads();
    }
#pragma unroll
    for (int m = 0; m < 4; m++) {
#pragma unroll
        for (int n = 0; n < 2; n++) {
            int col = n0 + wn * 32 + n * 16 + (lane & 15);
            float bv = bias[col];
#pragma unroll
            for (int r = 0; r < 4; r++) {
                int row = m0 + wm * 64 + m * 16 + ((lane >> 4) << 2) + r;
                out[(size_t)row * 512 + col] = acc[m][n][r] + bv;
            }
        }
    }
}

extern "C" void kernel_launch(void* const* d_in, const int* in_sizes, int n_in,
                              void* d_out, int out_size, void* d_ws, size_t ws_size,
                              hipStream_t stream) {
    const float* feat    = (const float*)d_in[0];
    const int*   pe_idx  = (const int*)d_in[3];
    const float* pret    = (const float*)d_in[5];
    const float* qw      = (const float*)d_in[6];
    const float* qb      = (const float*)d_in[7];
    const float* kvw     = (const float*)d_in[8];
    const float* kvb     = (const float*)d_in[9];
    const float* pew     = (const float*)d_in[10];
    const float* peb     = (const float*)d_in[11];
    const float* blank_k = (const float*)d_in[12];
    const float* blank_v = (const float*)d_in[13];
    const float* projw   = (const float*)d_in[14];
    const float* projb   = (const float*)d_in[15];

    char* ws = (char*)d_ws;
    unsigned short* featb  = (unsigned short*)(ws);                  // 4 MB (reused as attnO)
    unsigned short* wqkv   = (unsigned short*)(ws + 4194304);        // 1.5 MB
    unsigned short* projwb = (unsigned short*)(ws + 5767168);        // 0.5 MB
    float*          bqkv   = (float*)(ws + 6291456);                 // 6 KB
    unsigned short* peG    = (unsigned short*)(ws + 6297600);        // 128 KB
    unsigned short* Qf     = (unsigned short*)(ws + 6428672);        // 4 MB
    unsigned short* Kf     = (unsigned short*)(ws + 10622976);       // 4 MB
    unsigned short* Vf     = (unsigned short*)(ws + 14817280);       // 4 MB
    unsigned short* attnO  = featb;                                  // alias (featb dead after k_qkv)

    k_prep<<<dim3(5382), dim3(256), 0, stream>>>(feat, qw, qb, kvw, kvb, pew, peb, pret, projw,
                                                 featb, wqkv, bqkv, projwb, peG);
    k_qkv<<<dim3(24, 32), dim3(256), 0, stream>>>(featb, wqkv, bqkv, Qf, Kf, Vf);
    k_attn<<<dim3(512), dim3(256), 0, stream>>>(Qf, Kf, Vf, pe_idx, peG, blank_k, blank_v, attnO);
    k_proj<<<dim3(8, 32), dim3(256), 0, stream>>>(attnO, projwb, projb, (float*)d_out);
}

// Round 11
// 72.374 us; speedup vs baseline: 1.2929x; 1.0023x over previous
//
#include <hip/hip_runtime.h>
#include <hip/hip_fp16.h>

typedef __attribute__((ext_vector_type(8))) short short8;
typedef __attribute__((ext_vector_type(8))) __bf16 bf16x8;
typedef __attribute__((ext_vector_type(4))) float f32x4;
typedef __attribute__((ext_vector_type(16))) float f32x16;

#define DEV __device__ __forceinline__

DEV unsigned short f2bf(float f) {
    unsigned int u = __float_as_uint(f);
    return (unsigned short)((u + 0x7FFFu + ((u >> 16) & 1u)) >> 16);
}
DEV float bf2f(unsigned short s) { return __uint_as_float(((unsigned int)s) << 16); }
DEV bf16x8 asbf(short8 v) { return __builtin_bit_cast(bf16x8, v); }

// ---------------- prep kernel (feat cast + weight pack fused) ----------------
// peG layout: [hg(4)][4096][4] f16  (head h -> group h>>2, slot h&3)
__global__ __launch_bounds__(256) void k_prep(const float* __restrict__ feat,
                                              const float* __restrict__ qw, const float* __restrict__ qb,
                                              const float* __restrict__ kvw, const float* __restrict__ kvb,
                                              const float* __restrict__ pew, const float* __restrict__ peb,
                                              const float* __restrict__ pret, const float* __restrict__ projw,
                                              unsigned short* __restrict__ featb,
                                              unsigned short* __restrict__ wqkv, float* __restrict__ bqkv,
                                              unsigned short* __restrict__ projwb, unsigned short* __restrict__ peG) {
    const float scale = 0.17677669529663687f; // 1/sqrt(32)
    int i0 = blockIdx.x * 256 + threadIdx.x;
    if (i0 < 262144) {                        // feat f32 -> bf16, 8/thread
        const float4* f4 = (const float4*)feat + (size_t)i0 * 2;
        float4 a = f4[0], c = f4[1];
        short8 o;
        o[0] = (short)f2bf(a.x); o[1] = (short)f2bf(a.y);
        o[2] = (short)f2bf(a.z); o[3] = (short)f2bf(a.w);
        o[4] = (short)f2bf(c.x); o[5] = (short)f2bf(c.y);
        o[6] = (short)f2bf(c.z); o[7] = (short)f2bf(c.w);
        ((short8*)featb)[i0] = o;
        return;
    }
    int i = i0 - 262144;
    if (i < 786432) {                         // wqkv [1536][512]
        int o = i >> 9, k = i & 511;
        float v = (o < 512) ? qw[(o << 9) + k] * scale : kvw[((o - 512) << 9) + k];
        wqkv[i] = f2bf(v);
    } else if (i < 786432 + 262144) {
        int j = i - 786432;
        projwb[j] = f2bf(projw[j]);
    } else if (i < 786432 + 262144 + 1536) {
        int o = i - (786432 + 262144);
        bqkv[o] = (o < 512) ? qb[o] * scale : kvb[o - 512];
    } else if (i < 786432 + 262144 + 1536 + 65536) { // peG[h>>2][t][h&3] f16
        int j = i - (786432 + 262144 + 1536);
        int t = j >> 4, h = j & 15;
        float s = peb[h];
#pragma unroll
        for (int u = 0; u < 5; u++) s += pret[t * 5 + u] * pew[h * 5 + u];
        peG[(size_t)(h >> 2) * 16384 + t * 4 + (h & 3)] =
            __builtin_bit_cast(unsigned short, __float2half(s));
    }
}

// ---------------- QKV GEMM: 128x64 tile, 256 threads, grid (24,32)=768 (3/CU exact) ----------------
__global__ __launch_bounds__(256) void k_qkv(const unsigned short* __restrict__ A,
                                             const unsigned short* __restrict__ Bw,
                                             const float* __restrict__ bias,
                                             unsigned short* __restrict__ Qf,
                                             unsigned short* __restrict__ Kf,
                                             unsigned short* __restrict__ Vf) {
    __shared__ __align__(16) unsigned short As[128][72];
    __shared__ __align__(16) unsigned short Bs[64][72];
    int tid = threadIdx.x, lane = tid & 63, wid = tid >> 6;
    int m0 = blockIdx.y * 128, n0 = blockIdx.x * 64;
    int wm = wid >> 1, wn = wid & 1;
    f32x4 acc[4][2] = {};

    for (int k0 = 0; k0 < 512; k0 += 64) {
        {
            int row = tid >> 1, cs = (tid & 1) * 32;
            const short8* src = (const short8*)(A + (size_t)(m0 + row) * 512 + k0 + cs);
            short8* dst = (short8*)(&As[row][cs]);
            dst[0] = src[0]; dst[1] = src[1]; dst[2] = src[2]; dst[3] = src[3];
        }
        {
            int row = tid >> 2, cs = (tid & 3) * 16;
            const short8* src = (const short8*)(Bw + (size_t)(n0 + row) * 512 + k0 + cs);
            short8* dst = (short8*)(&Bs[row][cs]);
            dst[0] = src[0]; dst[1] = src[1];
        }
        __syncthreads();
#pragma unroll
        for (int kk = 0; kk < 64; kk += 32) {
            short8 a[4], b[2];
#pragma unroll
            for (int m = 0; m < 4; m++)
                a[m] = *(const short8*)(&As[wm * 64 + m * 16 + (lane & 15)][kk + ((lane >> 4) << 3)]);
#pragma unroll
            for (int n = 0; n < 2; n++)
                b[n] = *(const short8*)(&Bs[wn * 32 + n * 16 + (lane & 15)][kk + ((lane >> 4) << 3)]);
#pragma unroll
            for (int m = 0; m < 4; m++) {
#pragma unroll
                for (int n = 0; n < 2; n++)
                    acc[m][n] = __builtin_amdgcn_mfma_f32_16x16x32_bf16(asbf(a[m]), asbf(b[n]), acc[m][n], 0, 0, 0);
            }
        }
        __syncthreads();
    }
#pragma unroll
    for (int m = 0; m < 4; m++) {
#pragma unroll
        for (int n = 0; n < 2; n++) {
            int col = n0 + wn * 32 + n * 16 + (lane & 15);
            float bv = bias[col];
#pragma unroll
            for (int r = 0; r < 4; r++) {
                int row = m0 + wm * 64 + m * 16 + ((lane >> 4) << 2) + r;
                float v = acc[m][n][r] + bv;
                unsigned short bb = f2bf(v);
                int batch = row >> 10, nn = row & 1023;
                if (col < 512) {            // Q
                    int h = col >> 5, d = col & 31;
                    int bh = (batch << 4) + h;
                    int qt = nn >> 5, q5 = nn & 31;
                    int sub = d >> 4, hi2 = (d >> 3) & 1, j = d & 7;
                    Qf[((((size_t)(bh * 32 + qt) * 2 + sub) * 64) + hi2 * 32 + q5) * 8 + j] = bb;
                } else {
                    int oo = col - 512, h = oo >> 6, rem = oo & 63;
                    int bh = (batch << 4) + h;
                    int kt = nn >> 6, ks = (nn >> 5) & 1;
                    if (rem < 32) {         // K
                        int d = rem, half = d >> 4, hi2 = (d >> 3) & 1, j = d & 7, q5 = nn & 31;
                        Kf[((((size_t)((bh * 16 + kt) * 2 + ks) * 2 + half) * 64) + hi2 * 32 + q5) * 8 + j] = bb;
                    } else {                // V
                        int d = rem - 32, nb = nn & 31;
                        int half = nb >> 4, hi2 = (nb >> 3) & 1, j = nb & 7;
                        Vf[((((size_t)((bh * 16 + kt) * 2 + ks) * 2 + half) * 64) + hi2 * 32 + d) * 8 + j] = bb;
                    }
                }
            }
        }
    }
}

// ---------------- fused attention: 4 heads/block, 53.5KB LDS -> 3 blocks/CU ----------------
// grid 512: b=bid&3, qt=(bid>>2)&31, hg=bid>>7 (0..3)
// 256 threads = 4 waves; wave w -> head hg*4+w; q-tile 32; full k=1024 in 16 tiles of 64
__global__ __launch_bounds__(256, 3) void k_attn(const unsigned short* __restrict__ Qf,
                                                 const unsigned short* __restrict__ Kf,
                                                 const unsigned short* __restrict__ Vf,
                                                 const int* __restrict__ pe_idx,
                                                 const unsigned short* __restrict__ peG,
                                                 const float* __restrict__ blank_k,
                                                 const float* __restrict__ blank_v,
                                                 unsigned short* __restrict__ attnO) {
    __shared__ __align__(8) unsigned short peT4[4096][4];  // 32 KB: this hg's 4 heads, f16
    __shared__ unsigned short idxT[64][34];                // 4.35 KB transposed idx tile [k][q], u16
    __shared__ unsigned posS[4096];                        // 16 KB: 2048 els x 2 dwords, stride 2

    int tid = threadIdx.x, lane = tid & 63, w = tid >> 6;
    int q5 = lane & 31, hi = lane >> 5;
    int bid = blockIdx.x;
    int b = bid & 3, qt = (bid >> 2) & 31, hg = bid >> 7;
    int q0 = qt * 32;
    int head = hg * 4 + w, bh = (b << 4) + head;
    int dwsel = w >> 1, halfsel = w & 1;

    // stage peT4 (one-time): row r = tid + 256*j2, 8B coalesced from peG
    {
        const unsigned short* pg = peG + (size_t)hg * 16384;
#pragma unroll
        for (int j2 = 0; j2 < 16; j2++) {
            int r = tid + 256 * j2;
            *(uint2*)&peT4[r][0] = *(const uint2*)(pg + r * 4);
        }
    }

    // idx staging map: thread -> (q row sq, 8 consecutive k at sk8)
    int sq = tid >> 3, sk8 = (tid & 7) * 8;
    const int* pib = pe_idx + ((size_t)((b << 10) + q0 + sq)) * 1024 + sk8;

    short8 qf[2];
    float lb_, m_run, l_run;
    f32x16 accO = {};
    const f32x16 zero16 = {};

    {
        const unsigned short* qb_ = Qf + ((size_t)(bh * 32 + qt) * 2) * 512 + lane * 8;
        qf[0] = *(const short8*)(qb_);
        qf[1] = *(const short8*)(qb_ + 512);
        float dot = 0.f;
#pragma unroll
        for (int sub = 0; sub < 2; sub++) {
            const float* bk = blank_k + head * 32 + sub * 16 + hi * 8;
#pragma unroll
            for (int t = 0; t < 8; t++) dot += bf2f((unsigned short)qf[sub][t]) * bk[t];
        }
        dot += __shfl_xor(dot, 32, 64);
        lb_ = dot;
        m_run = dot;
        l_run = 1.0f;
    }

    // prologue: stage idx tile 0 (transposed, u16)
    {
        int4 a0 = *(const int4*)(pib);
        int4 a1 = *(const int4*)(pib + 4);
        idxT[sk8 + 0][sq] = (unsigned short)a0.x; idxT[sk8 + 1][sq] = (unsigned short)a0.y;
        idxT[sk8 + 2][sq] = (unsigned short)a0.z; idxT[sk8 + 3][sq] = (unsigned short)a0.w;
        idxT[sk8 + 4][sq] = (unsigned short)a1.x; idxT[sk8 + 5][sq] = (unsigned short)a1.y;
        idxT[sk8 + 6][sq] = (unsigned short)a1.z; idxT[sk8 + 7][sq] = (unsigned short)a1.w;
    }
    __syncthreads();   // peT4 + idxT(0) ready

    for (int kt = 0; kt < 16; kt++) {
        // ---- staging phase: gather pos rows once per (q,k), write posS stride-2 ----
#pragma unroll
        for (int j = 0; j < 8; j++) {
            int el = tid + 256 * j;                       // k-local = el>>5, q = el&31
            int idx = idxT[el >> 5][el & 31];
            uint2 pv = *(const uint2*)&peT4[idx][0];
            *(uint2*)&posS[el * 2] = pv;
        }
        __syncthreads();   // posS(kt) ready; idxT(kt) consumed

        // prefetch next idx tile into regs (latency hidden under compute)
        int4 n0_, n1_;
        if (kt < 15) {
            n0_ = *(const int4*)(pib + (kt + 1) * 64);
            n1_ = *(const int4*)(pib + (kt + 1) * 64 + 4);
        }

        // ---- compute phase ----
        // S^T = K x Q^T (32k x 32q), rows k=(r&3)+8*(r>>2)+4*hi, col q=q5
        f32x16 st[2];
#pragma unroll
        for (int ks = 0; ks < 2; ks++) {
            const unsigned short* kp = Kf + ((size_t)((bh * 16 + kt) * 2 + ks) * 2) * 512 + lane * 8;
            short8 kf0 = *(const short8*)(kp);
            short8 kf1 = *(const short8*)(kp + 512);
            st[ks] = __builtin_amdgcn_mfma_f32_32x32x16_bf16(asbf(kf0), asbf(qf[0]), zero16, 0, 0, 0);
            st[ks] = __builtin_amdgcn_mfma_f32_32x32x16_bf16(asbf(kf1), asbf(qf[1]), st[ks], 0, 0, 0);
        }
        // pos add: posS reads, bank = (2*q5+dwsel)%32 -> 2 lanes/bank (free)
#pragma unroll
        for (int ks = 0; ks < 2; ks++) {
#pragma unroll
            for (int r = 0; r < 16; r++) {
                int kl = (r & 3) + 8 * (r >> 2) + 4 * hi + 32 * ks;
                unsigned pd = posS[(kl * 32 + q5) * 2 + dwsel];
                __half2 h2 = __builtin_bit_cast(__half2, pd);
                st[ks][r] += halfsel ? __high2float(h2) : __low2float(h2);
            }
        }
        // tile max: tree reduction
        float tm[16];
#pragma unroll
        for (int i = 0; i < 16; i++) tm[i] = fmaxf(st[0][i], st[1][i]);
#pragma unroll
        for (int i = 0; i < 8; i++) tm[i] = fmaxf(tm[i], tm[i + 8]);
#pragma unroll
        for (int i = 0; i < 4; i++) tm[i] = fmaxf(tm[i], tm[i + 4]);
        float mx = fmaxf(fmaxf(tm[0], tm[1]), fmaxf(tm[2], tm[3]));
        mx = fmaxf(mx, __shfl_xor(mx, 32, 64));
        // defer-max (T13)
        if (!__all(mx <= m_run + 8.0f)) {
            float mn = fmaxf(m_run, mx);
            float fac = __expf(m_run - mn);
            m_run = mn;
            l_run *= fac;
#pragma unroll
            for (int r = 0; r < 16; r++) {
                int qrow = (r & 3) + 8 * (r >> 2) + 4 * hi;
                float facr = __shfl(fac, qrow, 64);
                accO[r] *= facr;
            }
        }
#pragma unroll
        for (int ks = 0; ks < 2; ks++)
#pragma unroll
            for (int r = 0; r < 16; r++)
                st[ks][r] = __expf(st[ks][r] - m_run);
        // sum: tree reduction
        float ts[16];
#pragma unroll
        for (int i = 0; i < 16; i++) ts[i] = st[0][i] + st[1][i];
#pragma unroll
        for (int i = 0; i < 8; i++) ts[i] += ts[i + 8];
#pragma unroll
        for (int i = 0; i < 4; i++) ts[i] += ts[i + 4];
        float sum = (ts[0] + ts[1]) + (ts[2] + ts[3]);
        sum += __shfl_xor(sum, 32, 64);
        l_run += sum;
        // P -> A-frag via v_cvt_pk_bf16_f32 + permlane32_swap (T12), then PV
#pragma unroll
        for (int ks = 0; ks < 2; ks++) {
            unsigned pk_[8];
#pragma unroll
            for (int i = 0; i < 8; i++) {
                float plo = st[ks][2 * i], phi = st[ks][2 * i + 1];
                asm("v_cvt_pk_bf16_f32 %0, %1, %2" : "=v"(pk_[i]) : "v"(plo), "v"(phi));
            }
            asm("v_permlane32_swap_b32 %0, %1" : "+v"(pk_[0]), "+v"(pk_[2]));
            asm("v_permlane32_swap_b32 %0, %1" : "+v"(pk_[1]), "+v"(pk_[3]));
            asm("v_permlane32_swap_b32 %0, %1" : "+v"(pk_[4]), "+v"(pk_[6]));
            asm("v_permlane32_swap_b32 %0, %1" : "+v"(pk_[5]), "+v"(pk_[7]));
            uint4 u0 = {pk_[0], pk_[1], pk_[2], pk_[3]};
            uint4 u1 = {pk_[4], pk_[5], pk_[6], pk_[7]};
            short8 pa0 = __builtin_bit_cast(short8, u0);
            short8 pa1 = __builtin_bit_cast(short8, u1);
            const unsigned short* vp = Vf + ((size_t)((bh * 16 + kt) * 2 + ks) * 2) * 512 + lane * 8;
            short8 vf0 = *(const short8*)(vp);
            short8 vf1 = *(const short8*)(vp + 512);
            accO = __builtin_amdgcn_mfma_f32_32x32x16_bf16(asbf(pa0), asbf(vf0), accO, 0, 0, 0);
            accO = __builtin_amdgcn_mfma_f32_32x32x16_bf16(asbf(pa1), asbf(vf1), accO, 0, 0, 0);
        }
        // write next idx tile (idxT dead since staging phase; visible after barrier)
        if (kt < 15) {
            idxT[sk8 + 0][sq] = (unsigned short)n0_.x; idxT[sk8 + 1][sq] = (unsigned short)n0_.y;
            idxT[sk8 + 2][sq] = (unsigned short)n0_.z; idxT[sk8 + 3][sq] = (unsigned short)n0_.w;
            idxT[sk8 + 4][sq] = (unsigned short)n1_.x; idxT[sk8 + 5][sq] = (unsigned short)n1_.y;
            idxT[sk8 + 6][sq] = (unsigned short)n1_.z; idxT[sk8 + 7][sq] = (unsigned short)n1_.w;
        }
        __syncthreads();   // posS consumed; idxT(kt+1) ready
    }

    // epilogue: direct attnO write with blank term.
    // accO[r] is output ROW qrow; l_run/m_run/lb_ live per-lane at q=q5 -> shfl per-row stats.
    {
        float inv = 1.0f / l_run;
        float bw = __expf(lb_ - m_run) * inv;
        float bv = blank_v[head * 32 + q5];
#pragma unroll
        for (int r = 0; r < 16; r++) {
            int qrow = (r & 3) + 8 * (r >> 2) + 4 * hi;
            float inv_r = __shfl(inv, qrow, 64);
            float bw_r = __shfl(bw, qrow, 64);
            float ov = accO[r] * inv_r + bw_r * bv;
            attnO[((size_t)((b << 10) + q0 + qrow)) * 512 + head * 32 + q5] = f2bf(ov);
        }
    }
}

// ---------------- final projection GEMM ----------------
__global__ __launch_bounds__(256) void k_proj(const unsigned short* __restrict__ A,
                                              const unsigned short* __restrict__ Bw,
                                              const float* __restrict__ bias,
                                              float* __restrict__ out) {
    __shared__ __align__(16) unsigned short As[128][72];
    __shared__ __align__(16) unsigned short Bs[64][72];
    int tid = threadIdx.x, lane = tid & 63, wid = tid >> 6;
    int m0 = blockIdx.y * 128, n0 = blockIdx.x * 64;
    int wm = wid >> 1, wn = wid & 1;
    f32x4 acc[4][2] = {};

    for (int k0 = 0; k0 < 512; k0 += 64) {
        {
            int row = tid >> 1, cs = (tid & 1) * 32;
            const short8* src = (const short8*)(A + (size_t)(m0 + row) * 512 + k0 + cs);
            short8* dst = (short8*)(&As[row][cs]);
            dst[0] = src[0]; dst[1] = src[1]; dst[2] = src[2]; dst[3] = src[3];
        }
        {
            int row = tid >> 2, cs = (tid & 3) * 16;
            const short8* src = (const short8*)(Bw + (size_t)(n0 + row) * 512 + k0 + cs);
            short8* dst = (short8*)(&Bs[row][cs]);
            dst[0] = src[0]; dst[1] = src[1];
        }
        __syncthreads();
#pragma unroll
        for (int kk = 0; kk < 64; kk += 32) {
            short8 a[4], b[2];
#pragma unroll
            for (int m = 0; m < 4; m++)
                a[m] = *(const short8*)(&As[wm * 64 + m * 16 + (lane & 15)][kk + ((lane >> 4) << 3)]);
#pragma unroll
            for (int n = 0; n < 2; n++)
                b[n] = *(const short8*)(&Bs[wn * 32 + n * 16 + (lane & 15)][kk + ((lane >> 4) << 3)]);
#pragma unroll
            for (int m = 0; m < 4; m++) {
#pragma unroll
                for (int n = 0; n < 2; n++)
                    acc[m][n] = __builtin_amdgcn_mfma_f32_16x16x32_bf16(asbf(a[m]), asbf(b[n]), acc[m][n], 0, 0, 0);
            }
        }
        __syncthreads();
    }
#pragma unroll
    for (int m = 0; m < 4; m++) {
#pragma unroll
        for (int n = 0; n < 2; n++) {
            int col = n0 + wn * 32 + n * 16 + (lane & 15);
            float bv = bias[col];
#pragma unroll
            for (int r = 0; r < 4; r++) {
                int row = m0 + wm * 64 + m * 16 + ((lane >> 4) << 2) + r;
                out[(size_t)row * 512 + col] = acc[m][n][r] + bv;
            }
        }
    }
}

extern "C" void kernel_launch(void* const* d_in, const int* in_sizes, int n_in,
                              void* d_out, int out_size, void* d_ws, size_t ws_size,
                              hipStream_t stream) {
    const float* feat    = (const float*)d_in[0];
    const int*   pe_idx  = (const int*)d_in[3];
    const float* pret    = (const float*)d_in[5];
    const float* qw      = (const float*)d_in[6];
    const float* qb      = (const float*)d_in[7];
    const float* kvw     = (const float*)d_in[8];
    const float* kvb     = (const float*)d_in[9];
    const float* pew     = (const float*)d_in[10];
    const float* peb     = (const float*)d_in[11];
    const float* blank_k = (const float*)d_in[12];
    const float* blank_v = (const float*)d_in[13];
    const float* projw   = (const float*)d_in[14];
    const float* projb   = (const float*)d_in[15];

    char* ws = (char*)d_ws;
    unsigned short* featb  = (unsigned short*)(ws);                  // 4 MB (reused as attnO)
    unsigned short* wqkv   = (unsigned short*)(ws + 4194304);        // 1.5 MB
    unsigned short* projwb = (unsigned short*)(ws + 5767168);        // 0.5 MB
    float*          bqkv   = (float*)(ws + 6291456);                 // 6 KB
    unsigned short* peG    = (unsigned short*)(ws + 6297600);        // 128 KB
    unsigned short* Qf     = (unsigned short*)(ws + 6428672);        // 4 MB
    unsigned short* Kf     = (unsigned short*)(ws + 10622976);       // 4 MB
    unsigned short* Vf     = (unsigned short*)(ws + 14817280);       // 4 MB
    unsigned short* attnO  = featb;                                  // alias (featb dead after k_qkv)

    k_prep<<<dim3(5382), dim3(256), 0, stream>>>(feat, qw, qb, kvw, kvb, pew, peb, pret, projw,
                                                 featb, wqkv, bqkv, projwb, peG);
    k_qkv<<<dim3(24, 32), dim3(256), 0, stream>>>(featb, wqkv, bqkv, Qf, Kf, Vf);
    k_attn<<<dim3(512), dim3(256), 0, stream>>>(Qf, Kf, Vf, pe_idx, peG, blank_k, blank_v, attnO);
    k_proj<<<dim3(8, 32), dim3(256), 0, stream>>>(attnO, projwb, projb, (float*)d_out);
}

// Round 12
// 71.626 us; speedup vs baseline: 1.3064x; 1.0104x over previous
//
#include <hip/hip_runtime.h>
#include <hip/hip_fp16.h>

typedef __attribute__((ext_vector_type(8))) short short8;
typedef __attribute__((ext_vector_type(8))) __bf16 bf16x8;
typedef __attribute__((ext_vector_type(4))) float f32x4;
typedef __attribute__((ext_vector_type(16))) float f32x16;

#define DEV __device__ __forceinline__

DEV unsigned short f2bf(float f) {
    unsigned int u = __float_as_uint(f);
    return (unsigned short)((u + 0x7FFFu + ((u >> 16) & 1u)) >> 16);
}
DEV float bf2f(unsigned short s) { return __uint_as_float(((unsigned int)s) << 16); }
DEV bf16x8 asbf(short8 v) { return __builtin_bit_cast(bf16x8, v); }

// ---------------- prep kernel (feat cast + weight pack fused) ----------------
// peG2 layout: [hg(8)][4096] dwords; dword = {f16 head hg*2, f16 head hg*2+1}
__global__ __launch_bounds__(256) void k_prep(const float* __restrict__ feat,
                                              const float* __restrict__ qw, const float* __restrict__ qb,
                                              const float* __restrict__ kvw, const float* __restrict__ kvb,
                                              const float* __restrict__ pew, const float* __restrict__ peb,
                                              const float* __restrict__ pret, const float* __restrict__ projw,
                                              unsigned short* __restrict__ featb,
                                              unsigned short* __restrict__ wqkv, float* __restrict__ bqkv,
                                              unsigned short* __restrict__ projwb, unsigned short* __restrict__ peG2) {
    const float scale = 0.17677669529663687f; // 1/sqrt(32)
    int i0 = blockIdx.x * 256 + threadIdx.x;
    if (i0 < 262144) {                        // feat f32 -> bf16, 8/thread
        const float4* f4 = (const float4*)feat + (size_t)i0 * 2;
        float4 a = f4[0], c = f4[1];
        short8 o;
        o[0] = (short)f2bf(a.x); o[1] = (short)f2bf(a.y);
        o[2] = (short)f2bf(a.z); o[3] = (short)f2bf(a.w);
        o[4] = (short)f2bf(c.x); o[5] = (short)f2bf(c.y);
        o[6] = (short)f2bf(c.z); o[7] = (short)f2bf(c.w);
        ((short8*)featb)[i0] = o;
        return;
    }
    int i = i0 - 262144;
    if (i < 786432) {                         // wqkv [1536][512]
        int o = i >> 9, k = i & 511;
        float v = (o < 512) ? qw[(o << 9) + k] * scale : kvw[((o - 512) << 9) + k];
        wqkv[i] = f2bf(v);
    } else if (i < 786432 + 262144) {
        int j = i - 786432;
        projwb[j] = f2bf(projw[j]);
    } else if (i < 786432 + 262144 + 1536) {
        int o = i - (786432 + 262144);
        bqkv[o] = (o < 512) ? qb[o] * scale : kvb[o - 512];
    } else if (i < 786432 + 262144 + 1536 + 65536) { // peG2[h>>1][t] halves
        int j = i - (786432 + 262144 + 1536);
        int t = j >> 4, h = j & 15;
        float s = peb[h];
#pragma unroll
        for (int u = 0; u < 5; u++) s += pret[t * 5 + u] * pew[h * 5 + u];
        peG2[(size_t)(h >> 1) * 8192 + t * 2 + (h & 1)] =
            __builtin_bit_cast(unsigned short, __float2half(s));
    }
}

// ---------------- QKV GEMM: 128x64 tile, 256 threads, grid (24,32)=768 (3/CU exact) ----------------
__global__ __launch_bounds__(256) void k_qkv(const unsigned short* __restrict__ A,
                                             const unsigned short* __restrict__ Bw,
                                             const float* __restrict__ bias,
                                             unsigned short* __restrict__ Qf,
                                             unsigned short* __restrict__ Kf,
                                             unsigned short* __restrict__ Vf) {
    __shared__ __align__(16) unsigned short As[128][72];
    __shared__ __align__(16) unsigned short Bs[64][72];
    int tid = threadIdx.x, lane = tid & 63, wid = tid >> 6;
    int m0 = blockIdx.y * 128, n0 = blockIdx.x * 64;
    int wm = wid >> 1, wn = wid & 1;
    f32x4 acc[4][2] = {};

    for (int k0 = 0; k0 < 512; k0 += 64) {
        {
            int row = tid >> 1, cs = (tid & 1) * 32;
            const short8* src = (const short8*)(A + (size_t)(m0 + row) * 512 + k0 + cs);
            short8* dst = (short8*)(&As[row][cs]);
            dst[0] = src[0]; dst[1] = src[1]; dst[2] = src[2]; dst[3] = src[3];
        }
        {
            int row = tid >> 2, cs = (tid & 3) * 16;
            const short8* src = (const short8*)(Bw + (size_t)(n0 + row) * 512 + k0 + cs);
            short8* dst = (short8*)(&Bs[row][cs]);
            dst[0] = src[0]; dst[1] = src[1];
        }
        __syncthreads();
#pragma unroll
        for (int kk = 0; kk < 64; kk += 32) {
            short8 a[4], b[2];
#pragma unroll
            for (int m = 0; m < 4; m++)
                a[m] = *(const short8*)(&As[wm * 64 + m * 16 + (lane & 15)][kk + ((lane >> 4) << 3)]);
#pragma unroll
            for (int n = 0; n < 2; n++)
                b[n] = *(const short8*)(&Bs[wn * 32 + n * 16 + (lane & 15)][kk + ((lane >> 4) << 3)]);
#pragma unroll
            for (int m = 0; m < 4; m++) {
#pragma unroll
                for (int n = 0; n < 2; n++)
                    acc[m][n] = __builtin_amdgcn_mfma_f32_16x16x32_bf16(asbf(a[m]), asbf(b[n]), acc[m][n], 0, 0, 0);
            }
        }
        __syncthreads();
    }
#pragma unroll
    for (int m = 0; m < 4; m++) {
#pragma unroll
        for (int n = 0; n < 2; n++) {
            int col = n0 + wn * 32 + n * 16 + (lane & 15);
            float bv = bias[col];
#pragma unroll
            for (int r = 0; r < 4; r++) {
                int row = m0 + wm * 64 + m * 16 + ((lane >> 4) << 2) + r;
                float v = acc[m][n][r] + bv;
                unsigned short bb = f2bf(v);
                int batch = row >> 10, nn = row & 1023;
                if (col < 512) {            // Q
                    int h = col >> 5, d = col & 31;
                    int bh = (batch << 4) + h;
                    int qt = nn >> 5, q5 = nn & 31;
                    int sub = d >> 4, hi2 = (d >> 3) & 1, j = d & 7;
                    Qf[((((size_t)(bh * 32 + qt) * 2 + sub) * 64) + hi2 * 32 + q5) * 8 + j] = bb;
                } else {
                    int oo = col - 512, h = oo >> 6, rem = oo & 63;
                    int bh = (batch << 4) + h;
                    int kt = nn >> 6, ks = (nn >> 5) & 1;
                    if (rem < 32) {         // K
                        int d = rem, half = d >> 4, hi2 = (d >> 3) & 1, j = d & 7, q5 = nn & 31;
                        Kf[((((size_t)((bh * 16 + kt) * 2 + ks) * 2 + half) * 64) + hi2 * 32 + q5) * 8 + j] = bb;
                    } else {                // V
                        int d = rem - 32, nb = nn & 31;
                        int half = nb >> 4, hi2 = (nb >> 3) & 1, j = nb & 7;
                        Vf[((((size_t)((bh * 16 + kt) * 2 + ks) * 2 + half) * 64) + hi2 * 32 + d) * 8 + j] = bb;
                    }
                }
            }
        }
    }
}

// ---------------- fused attention: 2 heads x in-block split-k, 4 blocks/CU ----------------
// grid 1024: b=bid&3, qt=(bid>>2)&31, hg=(bid>>7)&7
// 256 threads = 4 waves; wave w: head = hg*2+(w&1), khalf = w>>1 (k 0..511 / 512..1023)
__global__ __launch_bounds__(256, 4) void k_attn(const unsigned short* __restrict__ Qf,
                                                 const unsigned short* __restrict__ Kf,
                                                 const unsigned short* __restrict__ Vf,
                                                 const int* __restrict__ pe_idx,
                                                 const unsigned* __restrict__ peG2,
                                                 const float* __restrict__ blank_k,
                                                 const float* __restrict__ blank_v,
                                                 unsigned short* __restrict__ attnO) {
    __shared__ unsigned peT2[4096];        // 16 KB: dword = 2 heads' f16 pos
    __shared__ unsigned posS[128 * 33];    // 16.5 KB: [k 0..127][q 0..31] pad-33; reused for combine

    int tid = threadIdx.x, lane = tid & 63, w = tid >> 6;
    int q5 = lane & 31, hi = lane >> 5;
    int bid = blockIdx.x;
    int b = bid & 3, qt = (bid >> 2) & 31, hg = (bid >> 7) & 7;
    int q0 = qt * 32;
    int hl = w & 1, khalf = w >> 1;
    int head = hg * 2 + hl, bh = (b << 4) + head;

    // stage peT2 (one-time): 16 coalesced b32 per thread
    {
        const unsigned* pg = peG2 + (size_t)hg * 4096;
#pragma unroll
        for (int j2 = 0; j2 < 16; j2++) {
            int r = tid + 256 * j2;
            peT2[r] = pg[r];
        }
    }

    // staging map: thread -> q row sq, k-octet kg; 4 int4 idx loads cover 128 k (both halves)
    int sq = tid >> 3, kg = tid & 7;
    const int* pibase = pe_idx + ((size_t)((b << 10) + q0 + sq)) * 1024;

    short8 qf[2];
    float lb_, m_run, l_run;
    f32x16 accO = {};
    const f32x16 zero16 = {};

    {
        const unsigned short* qb_ = Qf + ((size_t)(bh * 32 + qt) * 2) * 512 + lane * 8;
        qf[0] = *(const short8*)(qb_);
        qf[1] = *(const short8*)(qb_ + 512);
        float dot = 0.f;
#pragma unroll
        for (int sub = 0; sub < 2; sub++) {
            const float* bk = blank_k + head * 32 + sub * 16 + hi * 8;
#pragma unroll
            for (int t = 0; t < 8; t++) dot += bf2f((unsigned short)qf[sub][t]) * bk[t];
        }
        dot += __shfl_xor(dot, 32, 64);
        lb_ = dot;
        m_run = (khalf == 0) ? dot : -1e30f;
        l_run = (khalf == 0) ? 1.0f : 0.0f;
    }

    // prologue: load idx (step 0) into regs
    int4 id4[4];
#pragma unroll
    for (int s = 0; s < 4; s++) {
        int col = (s < 2) ? (kg * 4 + 32 * s) : (512 + kg * 4 + 32 * (s - 2));
        id4[s] = *(const int4*)(pibase + col);
    }
    __syncthreads();   // peT2 ready

    for (int step = 0; step < 8; step++) {
        // ---- staging: gather both k-halves' tiles into posS[k][q] ----
#pragma unroll
        for (int s = 0; s < 4; s++) {
            int kb = kg * 4 + 32 * s;
            int id_[4] = {id4[s].x, id4[s].y, id4[s].z, id4[s].w};
#pragma unroll
            for (int c = 0; c < 4; c++)
                posS[(kb + c) * 33 + sq] = peT2[id_[c]];
        }
        __syncthreads();   // posS(step) ready

        // prefetch next step's idx into regs (hidden under compute)
        if (step < 7) {
#pragma unroll
            for (int s = 0; s < 4; s++) {
                int col = (s < 2) ? ((step + 1) * 64 + kg * 4 + 32 * s)
                                  : (512 + (step + 1) * 64 + kg * 4 + 32 * (s - 2));
                id4[s] = *(const int4*)(pibase + col);
            }
        }

        int ktg = khalf * 8 + step;
        // S^T = K x Q^T (32k x 32q), rows k=(r&3)+8*(r>>2)+4*hi, col q=q5
        f32x16 st[2];
#pragma unroll
        for (int ks = 0; ks < 2; ks++) {
            const unsigned short* kp = Kf + ((size_t)((bh * 16 + ktg) * 2 + ks) * 2) * 512 + lane * 8;
            short8 kf0 = *(const short8*)(kp);
            short8 kf1 = *(const short8*)(kp + 512);
            st[ks] = __builtin_amdgcn_mfma_f32_32x32x16_bf16(asbf(kf0), asbf(qf[0]), zero16, 0, 0, 0);
            st[ks] = __builtin_amdgcn_mfma_f32_32x32x16_bf16(asbf(kf1), asbf(qf[1]), st[ks], 0, 0, 0);
        }
        // pos add: posS[(khalf*64+kl)*33 + q5] -> bank (k+q)%32, conflict-free
#pragma unroll
        for (int ks = 0; ks < 2; ks++) {
#pragma unroll
            for (int r = 0; r < 16; r++) {
                int kl = (r & 3) + 8 * (r >> 2) + 4 * hi + 32 * ks;
                unsigned pd = posS[(khalf * 64 + kl) * 33 + q5];
                __half2 h2 = __builtin_bit_cast(__half2, pd);
                st[ks][r] += hl ? __high2float(h2) : __low2float(h2);
            }
        }
        // tile max: tree reduction
        float tm[16];
#pragma unroll
        for (int i = 0; i < 16; i++) tm[i] = fmaxf(st[0][i], st[1][i]);
#pragma unroll
        for (int i = 0; i < 8; i++) tm[i] = fmaxf(tm[i], tm[i + 8]);
#pragma unroll
        for (int i = 0; i < 4; i++) tm[i] = fmaxf(tm[i], tm[i + 4]);
        float mx = fmaxf(fmaxf(tm[0], tm[1]), fmaxf(tm[2], tm[3]));
        mx = fmaxf(mx, __shfl_xor(mx, 32, 64));
        // defer-max (T13)
        if (!__all(mx <= m_run + 8.0f)) {
            float mn = fmaxf(m_run, mx);
            float fac = __expf(m_run - mn);
            m_run = mn;
            l_run *= fac;
#pragma unroll
            for (int r = 0; r < 16; r++) {
                int qrow = (r & 3) + 8 * (r >> 2) + 4 * hi;
                float facr = __shfl(fac, qrow, 64);
                accO[r] *= facr;
            }
        }
#pragma unroll
        for (int ks = 0; ks < 2; ks++)
#pragma unroll
            for (int r = 0; r < 16; r++)
                st[ks][r] = __expf(st[ks][r] - m_run);
        // sum: tree reduction
        float ts[16];
#pragma unroll
        for (int i = 0; i < 16; i++) ts[i] = st[0][i] + st[1][i];
#pragma unroll
        for (int i = 0; i < 8; i++) ts[i] += ts[i + 8];
#pragma unroll
        for (int i = 0; i < 4; i++) ts[i] += ts[i + 4];
        float sum = (ts[0] + ts[1]) + (ts[2] + ts[3]);
        sum += __shfl_xor(sum, 32, 64);
        l_run += sum;
        // P -> A-frag via v_cvt_pk_bf16_f32 + permlane32_swap (T12), then PV
#pragma unroll
        for (int ks = 0; ks < 2; ks++) {
            unsigned pk_[8];
#pragma unroll
            for (int i = 0; i < 8; i++) {
                float plo = st[ks][2 * i], phi = st[ks][2 * i + 1];
                asm("v_cvt_pk_bf16_f32 %0, %1, %2" : "=v"(pk_[i]) : "v"(plo), "v"(phi));
            }
            asm("v_permlane32_swap_b32 %0, %1" : "+v"(pk_[0]), "+v"(pk_[2]));
            asm("v_permlane32_swap_b32 %0, %1" : "+v"(pk_[1]), "+v"(pk_[3]));
            asm("v_permlane32_swap_b32 %0, %1" : "+v"(pk_[4]), "+v"(pk_[6]));
            asm("v_permlane32_swap_b32 %0, %1" : "+v"(pk_[5]), "+v"(pk_[7]));
            uint4 u0 = {pk_[0], pk_[1], pk_[2], pk_[3]};
            uint4 u1 = {pk_[4], pk_[5], pk_[6], pk_[7]};
            short8 pa0 = __builtin_bit_cast(short8, u0);
            short8 pa1 = __builtin_bit_cast(short8, u1);
            const unsigned short* vp = Vf + ((size_t)((bh * 16 + ktg) * 2 + ks) * 2) * 512 + lane * 8;
            short8 vf0 = *(const short8*)(vp);
            short8 vf1 = *(const short8*)(vp + 512);
            accO = __builtin_amdgcn_mfma_f32_32x32x16_bf16(asbf(pa0), asbf(vf0), accO, 0, 0, 0);
            accO = __builtin_amdgcn_mfma_f32_32x32x16_bf16(asbf(pa1), asbf(vf1), accO, 0, 0, 0);
        }
        __syncthreads();   // posS consumed by all waves; next staging may overwrite
    }

    // ---- in-block split-k combine (posS reused as scratch) ----
    float* fb = (float*)posS;            // comb[hl][lane][17] then mS[2][32], lS[2][32]
    float* mS = fb + 2176;
    float* lS = mS + 64;
    if (khalf == 1) {
#pragma unroll
        for (int r = 0; r < 16; r++)
            fb[(hl * 64 + lane) * 17 + r] = accO[r];
        if (hi == 0) {
            mS[hl * 32 + q5] = m_run;
            lS[hl * 32 + q5] = l_run;
        }
    }
    __syncthreads();
    if (khalf == 0) {
        float mB = mS[hl * 32 + q5], lB = lS[hl * 32 + q5];
        float M = fmaxf(m_run, mB);
        float eA = __expf(m_run - M), eB = __expf(mB - M);
        float L = l_run * eA + lB * eB;
        float inv = 1.0f / L;
        float bw = __expf(lb_ - M) * inv;
        float bv = blank_v[head * 32 + q5];
#pragma unroll
        for (int r = 0; r < 16; r++) {
            int qrow = (r & 3) + 8 * (r >> 2) + 4 * hi;
            float eA_r = __shfl(eA, qrow, 64);
            float eB_r = __shfl(eB, qrow, 64);
            float inv_r = __shfl(inv, qrow, 64);
            float bw_r = __shfl(bw, qrow, 64);
            float accB = fb[(hl * 64 + lane) * 17 + r];
            float ov = (accO[r] * eA_r + accB * eB_r) * inv_r + bw_r * bv;
            attnO[((size_t)((b << 10) + q0 + qrow)) * 512 + head * 32 + q5] = f2bf(ov);
        }
    }
}

// ---------------- final projection GEMM ----------------
__global__ __launch_bounds__(256) void k_proj(const unsigned short* __restrict__ A,
                                              const unsigned short* __restrict__ Bw,
                                              const float* __restrict__ bias,
                                              float* __restrict__ out) {
    __shared__ __align__(16) unsigned short As[128][72];
    __shared__ __align__(16) unsigned short Bs[64][72];
    int tid = threadIdx.x, lane = tid & 63, wid = tid >> 6;
    int m0 = blockIdx.y * 128, n0 = blockIdx.x * 64;
    int wm = wid >> 1, wn = wid & 1;
    f32x4 acc[4][2] = {};

    for (int k0 = 0; k0 < 512; k0 += 64) {
        {
            int row = tid >> 1, cs = (tid & 1) * 32;
            const short8* src = (const short8*)(A + (size_t)(m0 + row) * 512 + k0 + cs);
            short8* dst = (short8*)(&As[row][cs]);
            dst[0] = src[0]; dst[1] = src[1]; dst[2] = src[2]; dst[3] = src[3];
        }
        {
            int row = tid >> 2, cs = (tid & 3) * 16;
            const short8* src = (const short8*)(Bw + (size_t)(n0 + row) * 512 + k0 + cs);
            short8* dst = (short8*)(&Bs[row][cs]);
            dst[0] = src[0]; dst[1] = src[1];
        }
        __syncthreads();
#pragma unroll
        for (int kk = 0; kk < 64; kk += 32) {
            short8 a[4], b[2];
#pragma unroll
            for (int m = 0; m < 4; m++)
                a[m] = *(const short8*)(&As[wm * 64 + m * 16 + (lane & 15)][kk + ((lane >> 4) << 3)]);
#pragma unroll
            for (int n = 0; n < 2; n++)
                b[n] = *(const short8*)(&Bs[wn * 32 + n * 16 + (lane & 15)][kk + ((lane >> 4) << 3)]);
#pragma unroll
            for (int m = 0; m < 4; m++) {
#pragma unroll
                for (int n = 0; n < 2; n++)
                    acc[m][n] = __builtin_amdgcn_mfma_f32_16x16x32_bf16(asbf(a[m]), asbf(b[n]), acc[m][n], 0, 0, 0);
            }
        }
        __syncthreads();
    }
#pragma unroll
    for (int m = 0; m < 4; m++) {
#pragma unroll
        for (int n = 0; n < 2; n++) {
            int col = n0 + wn * 32 + n * 16 + (lane & 15);
            float bv = bias[col];
#pragma unroll
            for (int r = 0; r < 4; r++) {
                int row = m0 + wm * 64 + m * 16 + ((lane >> 4) << 2) + r;
                out[(size_t)row * 512 + col] = acc[m][n][r] + bv;
            }
        }
    }
}

extern "C" void kernel_launch(void* const* d_in, const int* in_sizes, int n_in,
                              void* d_out, int out_size, void* d_ws, size_t ws_size,
                              hipStream_t stream) {
    const float* feat    = (const float*)d_in[0];
    const int*   pe_idx  = (const int*)d_in[3];
    const float* pret    = (const float*)d_in[5];
    const float* qw      = (const float*)d_in[6];
    const float* qb      = (const float*)d_in[7];
    const float* kvw     = (const float*)d_in[8];
    const float* kvb     = (const float*)d_in[9];
    const float* pew     = (const float*)d_in[10];
    const float* peb     = (const float*)d_in[11];
    const float* blank_k = (const float*)d_in[12];
    const float* blank_v = (const float*)d_in[13];
    const float* projw   = (const float*)d_in[14];
    const float* projb   = (const float*)d_in[15];

    char* ws = (char*)d_ws;
    unsigned short* featb  = (unsigned short*)(ws);                  // 4 MB (reused as attnO)
    unsigned short* wqkv   = (unsigned short*)(ws + 4194304);        // 1.5 MB
    unsigned short* projwb = (unsigned short*)(ws + 5767168);        // 0.5 MB
    float*          bqkv   = (float*)(ws + 6291456);                 // 6 KB
    unsigned short* peG2   = (unsigned short*)(ws + 6297600);        // 128 KB
    unsigned short* Qf     = (unsigned short*)(ws + 6428672);        // 4 MB
    unsigned short* Kf     = (unsigned short*)(ws + 10622976);       // 4 MB
    unsigned short* Vf     = (unsigned short*)(ws + 14817280);       // 4 MB
    unsigned short* attnO  = featb;                                  // alias (featb dead after k_qkv)

    k_prep<<<dim3(5382), dim3(256), 0, stream>>>(feat, qw, qb, kvw, kvb, pew, peb, pret, projw,
                                                 featb, wqkv, bqkv, projwb, peG2);
    k_qkv<<<dim3(24, 32), dim3(256), 0, stream>>>(featb, wqkv, bqkv, Qf, Kf, Vf);
    k_attn<<<dim3(1024), dim3(256), 0, stream>>>(Qf, Kf, Vf, pe_idx, (const unsigned*)peG2,
                                                 blank_k, blank_v, attnO);
    k_proj<<<dim3(8, 32), dim3(256), 0, stream>>>(attnO, projwb, projb, (float*)d_out);
}